// Round 2
// baseline (3534.781 us; speedup 1.0000x reference)
//
#include <hip/hip_runtime.h>
#include <math.h>

#define BLK 256

__device__ __forceinline__ float celu1(float x){ return x > 0.f ? x : (expf(x) - 1.f); }
__device__ __forceinline__ float softplus1(float x){ return fmaxf(x, 0.f) + log1pf(expf(-fabsf(x))); }
// valid only for v >= 0 with zero-initialized destination
__device__ __forceinline__ void atomicMaxNonneg(float* p, float v){
    atomicMax((int*)p, __float_as_int(v));
}

// ---------- stage 1 voxel mean pool: scatter pos -> ps1 sums + counts ----------
__global__ void k_scatter1(const float* __restrict__ pos,
                           const int* __restrict__ cl1,
                           float* __restrict__ ps1, float* __restrict__ cnt1, int N){
    int i = blockIdx.x * BLK + threadIdx.x;
    if (i >= N) return;
    int c = cl1[i];
    atomicAdd(&ps1[3*c+0], pos[3*i+0]);
    atomicAdd(&ps1[3*c+1], pos[3*i+1]);
    atomicAdd(&ps1[3*c+2], pos[3*i+2]);
    atomicAdd(&cnt1[c], 1.0f);
}

__global__ void k_norm(float* __restrict__ ps, const float* __restrict__ cnt, int M){
    int m = blockIdx.x * BLK + threadIdx.x;
    if (m >= M) return;
    float c = fmaxf(cnt[m], 1.0f);
    ps[3*m+0] = ps[3*m+0] / c;
    ps[3*m+1] = ps[3*m+1] / c;
    ps[3*m+2] = ps[3*m+2] / c;
}

// ---------- stage 1 message: msg = relu([rgb, pos - ps1[c]] @ W1l + b1l), seg-max ----------
__global__ void k_msg1(const float* __restrict__ rgb,
                       const float* __restrict__ pos,
                       const int* __restrict__ cl1,
                       const float* __restrict__ ps1,
                       const float* __restrict__ W1l,
                       const float* __restrict__ b1l,
                       float* __restrict__ agg1, int N){
    __shared__ float Ws[64];
    __shared__ float bs[16];
    if (threadIdx.x < 64) Ws[threadIdx.x] = W1l[threadIdx.x];
    if (threadIdx.x < 16) bs[threadIdx.x] = b1l[threadIdx.x];
    __syncthreads();
    int i = blockIdx.x * BLK + threadIdx.x;
    if (i >= N) return;
    int c = cl1[i];
    float in0 = rgb[i];
    float r0 = pos[3*i+0] - ps1[3*c+0];
    float r1 = pos[3*i+1] - ps1[3*c+1];
    float r2 = pos[3*i+2] - ps1[3*c+2];
    float* dst = agg1 + (size_t)c * 16;
    #pragma unroll
    for (int j = 0; j < 16; ++j){
        float v = bs[j] + in0*Ws[j] + r0*Ws[16+j] + r1*Ws[32+j] + r2*Ws[48+j];
        v = fmaxf(v, 0.0f);
        atomicMaxNonneg(&dst[j], v);
    }
}

// ---------- stage 2 voxel mean pool ----------
__global__ void k_scatter2(const float* __restrict__ ps1,
                           const int* __restrict__ cl2,
                           float* __restrict__ ps2, float* __restrict__ cnt2, int M1){
    int m = blockIdx.x * BLK + threadIdx.x;
    if (m >= M1) return;
    int c = cl2[m];
    atomicAdd(&ps2[3*c+0], ps1[3*m+0]);
    atomicAdd(&ps2[3*c+1], ps1[3*m+1]);
    atomicAdd(&ps2[3*c+2], ps1[3*m+2]);
    atomicAdd(&cnt2[c], 1.0f);
}

// ---------- stage 2: fused f1 = celu(agg1 @ W1g + b1g); msg2 = relu([f1, rel] @ W2l + b2l); seg-max ----------
__global__ void k_stage2(const float* __restrict__ agg1,
                         const float* __restrict__ ps1,
                         const float* __restrict__ ps2,
                         const int* __restrict__ cl2,
                         const float* __restrict__ W1g,
                         const float* __restrict__ b1g,
                         const float* __restrict__ W2l,
                         const float* __restrict__ b2l,
                         float* __restrict__ agg2, int M1){
    __shared__ float W1gs[16*32];
    __shared__ float b1gs[32];
    __shared__ float W2ls[35*64];
    __shared__ float b2ls[64];
    for (int t = threadIdx.x; t < 16*32; t += BLK) W1gs[t] = W1g[t];
    for (int t = threadIdx.x; t < 32;    t += BLK) b1gs[t] = b1g[t];
    for (int t = threadIdx.x; t < 35*64; t += BLK) W2ls[t] = W2l[t];
    for (int t = threadIdx.x; t < 64;    t += BLK) b2ls[t] = b2l[t];
    __syncthreads();
    int m = blockIdx.x * BLK + threadIdx.x;
    if (m >= M1) return;

    float a[16];
    const float* ar = agg1 + (size_t)m * 16;
    #pragma unroll
    for (int k = 0; k < 16; ++k) a[k] = ar[k];

    float in[35];
    #pragma unroll
    for (int j = 0; j < 32; ++j){
        float v = b1gs[j];
        #pragma unroll
        for (int k = 0; k < 16; ++k) v += a[k] * W1gs[k*32 + j];
        in[j] = celu1(v);
    }
    int c = cl2[m];
    in[32] = ps1[3*m+0] - ps2[3*c+0];
    in[33] = ps1[3*m+1] - ps2[3*c+1];
    in[34] = ps1[3*m+2] - ps2[3*c+2];

    float* dst = agg2 + (size_t)c * 64;
    for (int j = 0; j < 64; ++j){
        float v = b2ls[j];
        #pragma unroll
        for (int k = 0; k < 35; ++k) v += in[k] * W2ls[k*64 + j];
        v = fmaxf(v, 0.0f);
        atomicMaxNonneg(&dst[j], v);
    }
}

// ---------- f2 = celu(agg2 @ W2g + b2g), stored fp32 ----------
__global__ void k_f2(const float* __restrict__ agg2,
                     const float* __restrict__ W2g,
                     const float* __restrict__ b2g,
                     float* __restrict__ f2, int M2){
    __shared__ float Ws[64*128];   // 32 KB
    __shared__ float bs[128];
    for (int t = threadIdx.x; t < 64*128; t += BLK) Ws[t] = W2g[t];
    for (int t = threadIdx.x; t < 128;    t += BLK) bs[t] = b2g[t];
    __syncthreads();
    int total = M2 * 128;
    int stride = gridDim.x * BLK;
    for (int idx = blockIdx.x * BLK + threadIdx.x; idx < total; idx += stride){
        int m = idx >> 7, j = idx & 127;
        const float* ar = agg2 + (size_t)m * 64;
        float v = bs[j];
        #pragma unroll
        for (int k = 0; k < 64; ++k) v += ar[k] * Ws[k*128 + j];
        f2[idx] = celu1(v);
    }
}

// ---------- stage 3 message: msg3 = relu([f2, ps2] @ W3l + b3l), seg-max by glimpse ----------
// W3l is 131x128 f32 = 67 KB > 64 KB LDS limit -> split output channels into 2 halves (gridDim.y)
// thread = (point m, 16-wide output chunk within the 64-wide half)
__global__ void k_msg3(const float* __restrict__ f2,
                       const float* __restrict__ ps2,
                       const int* __restrict__ b2i,
                       const float* __restrict__ W3l,
                       const float* __restrict__ b3l,
                       float* __restrict__ agg3, int M2){
    __shared__ float Ws[131*64];   // 33.5 KB: column slice [*, half*64 .. half*64+63]
    __shared__ float bs[64];
    const int half = blockIdx.y;
    const int cbase = half * 64;
    for (int t = threadIdx.x; t < 131*64; t += BLK){
        int row = t >> 6, col = t & 63;
        Ws[t] = W3l[row*128 + cbase + col];
    }
    if (threadIdx.x < 64) bs[threadIdx.x] = b3l[cbase + threadIdx.x];
    __syncthreads();
    int idx = blockIdx.x * BLK + threadIdx.x;
    if (idx >= M2 * 4) return;
    int m = idx >> 2;
    int j0 = (idx & 3) * 16;   // within the 64-wide half

    float acc[16];
    #pragma unroll
    for (int jj = 0; jj < 16; ++jj) acc[jj] = bs[j0 + jj];

    const float* fr = f2 + (size_t)m * 128;
    for (int k0 = 0; k0 < 128; k0 += 4){
        float4 raw = *(const float4*)(fr + k0);   // rows are 512 B aligned
        float xs[4] = {raw.x, raw.y, raw.z, raw.w};
        #pragma unroll
        for (int kk = 0; kk < 4; ++kk){
            float x = xs[kk];
            const float* wr = Ws + (k0 + kk)*64 + j0;
            #pragma unroll
            for (int jj = 0; jj < 16; ++jj) acc[jj] += x * wr[jj];
        }
    }
    #pragma unroll
    for (int k = 0; k < 3; ++k){
        float x = ps2[3*m + k];
        const float* wr = Ws + (128 + k)*64 + j0;
        #pragma unroll
        for (int jj = 0; jj < 16; ++jj) acc[jj] += x * wr[jj];
    }
    int g = b2i[m];
    float* dst = agg3 + (size_t)g * 128 + cbase + j0;
    #pragma unroll
    for (int jj = 0; jj < 16; ++jj){
        float v = fmaxf(acc[jj], 0.0f);
        atomicMaxNonneg(&dst[jj], v);
    }
}

// ---------- head: f3 = celu(agg3 @ W3g + b3g); out = f3 @ Wlin + blin; reparam ----------
// one block per glimpse, 256 threads = one output channel each
__global__ void k_head(const float* __restrict__ agg3,
                       const float* __restrict__ W3g,
                       const float* __restrict__ b3g,
                       const float* __restrict__ Wlin,
                       const float* __restrict__ blin,
                       const float* __restrict__ eps,
                       float* __restrict__ out, int G){
    __shared__ float a3[128];
    __shared__ float f3s[256];
    __shared__ float hs[256];
    int g = blockIdx.x;
    int j = threadIdx.x;
    if (j < 128) a3[j] = agg3[(size_t)g*128 + j];
    __syncthreads();

    float v = b3g[j];
    for (int k = 0; k < 128; ++k) v += a3[k] * W3g[k*256 + j];
    v = celu1(v);
    f3s[j] = v;
    const size_t o_zm = (size_t)64*G, o_mu = (size_t)128*G, o_sg = (size_t)256*G, o_f3 = (size_t)384*G;
    out[o_f3 + (size_t)g*256 + j] = v;
    __syncthreads();

    float h = blin[j];
    for (int k = 0; k < 256; ++k) h += f3s[k] * Wlin[k*256 + j];
    hs[j] = h;
    __syncthreads();

    if (j < 128){
        float mu = hs[j];
        float sg = softplus1(hs[128 + j]);
        float z = mu + sg * eps[(size_t)g*128 + j];
        out[o_mu + (size_t)g*128 + j] = mu;
        out[o_sg + (size_t)g*128 + j] = sg;
        if (j < 64) out[(size_t)g*64 + j] = z;
        else        out[o_zm + (size_t)g*64 + (j - 64)] = z;
    }
}

extern "C" void kernel_launch(void* const* d_in, const int* in_sizes, int n_in,
                              void* d_out, int out_size, void* d_ws, size_t ws_size,
                              hipStream_t stream) {
    const float* rgb  = (const float*)d_in[0];
    const float* pos  = (const float*)d_in[1];
    const float* W1l  = (const float*)d_in[3];
    const float* b1l  = (const float*)d_in[4];
    const float* W1g  = (const float*)d_in[5];
    const float* b1g  = (const float*)d_in[6];
    const float* W2l  = (const float*)d_in[7];
    const float* b2l  = (const float*)d_in[8];
    const float* W2g  = (const float*)d_in[9];
    const float* b2g  = (const float*)d_in[10];
    const float* W3l  = (const float*)d_in[11];
    const float* b3l  = (const float*)d_in[12];
    const float* W3g  = (const float*)d_in[13];
    const float* b3g  = (const float*)d_in[14];
    const float* Wlin = (const float*)d_in[15];
    const float* blin = (const float*)d_in[16];
    const float* eps  = (const float*)d_in[17];
    const int* cl1 = (const int*)d_in[19];
    const int* cl2 = (const int*)d_in[20];
    const int* b2i = (const int*)d_in[21];

    const int N  = in_sizes[19];        // points (cluster1 length)
    const int G  = in_sizes[17] / 128;  // glimpses, from eps [G,128]
    const int M1 = in_sizes[20];        // level-1 voxels (cluster2 length)
    const int M2 = in_sizes[21];        // level-2 voxels (batch2 length)

    // workspace layout (bytes, 256-aligned); f2 (fp32, 512B/row) aliases agg1 (disjoint lifetimes)
    char* ws = (char*)d_ws;
    auto al = [](size_t x){ return (x + 255) & ~(size_t)255; };
    size_t off = 0;
    float* ps1  = (float*)(ws + off); off = al(off + 12ull*M1);
    float* cnt1 = (float*)(ws + off); off = al(off + 4ull*M1);
    size_t uni  = ((size_t)64*M1 > (size_t)512*M2) ? (size_t)64*M1 : (size_t)512*M2;
    float* agg1 = (float*)(ws + off);
    float* f2   = (float*)(ws + off);
    off = al(off + uni);
    float* ps2  = (float*)(ws + off); off = al(off + 12ull*M2);
    float* cnt2 = (float*)(ws + off); off = al(off + 4ull*M2);
    float* agg2 = (float*)(ws + off); off = al(off + 256ull*M2);
    float* agg3 = (float*)(ws + off); off = al(off + 512ull*G);
    size_t need = off;
    if (need > ws_size) return;  // scratch too small -> will show as validation failure

    hipMemsetAsync(d_ws, 0, need, stream);

    k_scatter1<<<(N  + BLK-1)/BLK, BLK, 0, stream>>>(pos, cl1, ps1, cnt1, N);
    k_norm    <<<(M1 + BLK-1)/BLK, BLK, 0, stream>>>(ps1, cnt1, M1);
    k_msg1    <<<(N  + BLK-1)/BLK, BLK, 0, stream>>>(rgb, pos, cl1, ps1, W1l, b1l, agg1, N);
    k_scatter2<<<(M1 + BLK-1)/BLK, BLK, 0, stream>>>(ps1, cl2, ps2, cnt2, M1);
    k_norm    <<<(M2 + BLK-1)/BLK, BLK, 0, stream>>>(ps2, cnt2, M2);
    k_stage2  <<<(M1 + BLK-1)/BLK, BLK, 0, stream>>>(agg1, ps1, ps2, cl2, W1g, b1g, W2l, b2l, agg2, M1);
    int grid_f2 = (M2*128 + BLK-1)/BLK; if (grid_f2 > 4096) grid_f2 = 4096;
    k_f2      <<<grid_f2, BLK, 0, stream>>>(agg2, W2g, b2g, f2, M2);
    dim3 g3((M2*4 + BLK-1)/BLK, 2);
    k_msg3    <<<g3, BLK, 0, stream>>>(f2, ps2, b2i, W3l, b3l, agg3, M2);
    k_head    <<<G, 256, 0, stream>>>(agg3, W3g, b3g, Wlin, blin, eps, (float*)d_out, G);
}

// Round 3
// 594.682 us; speedup vs baseline: 5.9440x; 5.9440x over previous
//
#include <hip/hip_runtime.h>
#include <math.h>

#define N1CAP 768
#define N2CAP 224
#define CH 32

__device__ __forceinline__ float celu1(float x){ return x > 0.f ? x : (expf(x) - 1.f); }
__device__ __forceinline__ float softplus1(float x){ return fmaxf(x, 0.f) + log1pf(expf(-fabsf(x))); }
// valid only for v >= 0 with zero-initialized destination (works on LDS or global pointers)
__device__ __forceinline__ void atomicMaxNonneg(float* p, float v){
    atomicMax((int*)p, __float_as_int(v));
}

// ================= kernel A: per-glimpse stage 1 =================
// points [g*P,(g+1)*P) -> ps1 mean + agg1 = segmax(relu([rgb,rel]@W1l+b1l))
__global__ __launch_bounds__(256) void kA(const float* __restrict__ rgb,
                                          const float* __restrict__ pos,
                                          const int* __restrict__ cl1,
                                          const float* __restrict__ W1l,
                                          const float* __restrict__ b1l,
                                          float* __restrict__ ps1,
                                          float* __restrict__ agg1,
                                          float* __restrict__ cnt1,
                                          int* __restrict__ seg1, int P){
    __shared__ float shx[N1CAP], shy[N1CAP], shz[N1CAP], shc[N1CAP];
    __shared__ float sha[N1CAP*16];
    __shared__ int red[2];
    const int g = blockIdx.x, tid = threadIdx.x;
    const int base = g * P;

    if (tid == 0){ red[0] = 0x7fffffff; red[1] = -1; }
    __syncthreads();
    int mn = 0x7fffffff, mx = -1;
    for (int i = tid; i < P; i += 256){ int c = cl1[base+i]; mn = min(mn,c); mx = max(mx,c); }
    atomicMin(&red[0], mn); atomicMax(&red[1], mx);
    __syncthreads();
    const int s1 = red[0];
    const int n1 = red[1] - red[0] + 1;
    const bool fast = (n1 <= N1CAP);

    if (fast){
        for (int l = tid; l < n1; l += 256){ shx[l]=0.f; shy[l]=0.f; shz[l]=0.f; shc[l]=0.f; }
        for (int t = tid; t < n1*16; t += 256) sha[t] = 0.f;
        __syncthreads();
        for (int i = tid; i < P; i += 256){
            int idx = base + i; int c = cl1[idx] - s1;
            atomicAdd(&shx[c], pos[3*idx+0]);
            atomicAdd(&shy[c], pos[3*idx+1]);
            atomicAdd(&shz[c], pos[3*idx+2]);
            atomicAdd(&shc[c], 1.0f);
        }
        __syncthreads();
        for (int l = tid; l < n1; l += 256){
            float ic = 1.0f / shc[l];   // count >= 1 guaranteed
            shx[l] *= ic; shy[l] *= ic; shz[l] *= ic;
        }
        __syncthreads();
        for (int i = tid; i < P; i += 256){
            int idx = base + i; int c = cl1[idx] - s1;
            float in0 = rgb[idx];
            float r0 = pos[3*idx+0] - shx[c];
            float r1 = pos[3*idx+1] - shy[c];
            float r2 = pos[3*idx+2] - shz[c];
            float* dst = &sha[c*16];
            #pragma unroll
            for (int j = 0; j < 16; ++j){  // j uniform -> scalar weight loads
                float v = b1l[j] + in0*W1l[j] + r0*W1l[16+j] + r1*W1l[32+j] + r2*W1l[48+j];
                atomicMaxNonneg(&dst[j], fmaxf(v, 0.0f));
            }
        }
        __syncthreads();
        for (int t = tid; t < n1*3; t += 256){
            int l = t/3, d = t - 3*l;
            ps1[(size_t)s1*3 + t] = (d==0) ? shx[l] : ((d==1) ? shy[l] : shz[l]);
        }
        float4* a4 = (float4*)(agg1 + (size_t)s1*16);
        const float4* s4 = (const float4*)sha;
        for (int t = tid; t < n1*4; t += 256) a4[t] = s4[t];
    } else {
        // rare fallback: global atomics into this block's exclusive rows
        for (int t = tid; t < n1;    t += 256) cnt1[s1+t] = 0.f;
        for (int t = tid; t < n1*3;  t += 256) ps1[(size_t)s1*3+t] = 0.f;
        for (int t = tid; t < n1*16; t += 256) agg1[(size_t)s1*16+t] = 0.f;
        __syncthreads();
        for (int i = tid; i < P; i += 256){
            int idx = base + i; int c = cl1[idx];
            atomicAdd(&ps1[3*c+0], pos[3*idx+0]);
            atomicAdd(&ps1[3*c+1], pos[3*idx+1]);
            atomicAdd(&ps1[3*c+2], pos[3*idx+2]);
            atomicAdd(&cnt1[c], 1.0f);
        }
        __syncthreads();
        for (int l = tid; l < n1; l += 256){
            float ic = 1.0f / cnt1[s1+l];
            ps1[(size_t)(s1+l)*3+0] *= ic; ps1[(size_t)(s1+l)*3+1] *= ic; ps1[(size_t)(s1+l)*3+2] *= ic;
        }
        __syncthreads();
        for (int i = tid; i < P; i += 256){
            int idx = base + i; int c = cl1[idx];
            float in0 = rgb[idx];
            float r0 = pos[3*idx+0] - ps1[3*c+0];
            float r1 = pos[3*idx+1] - ps1[3*c+1];
            float r2 = pos[3*idx+2] - ps1[3*c+2];
            #pragma unroll
            for (int j = 0; j < 16; ++j){
                float v = b1l[j] + in0*W1l[j] + r0*W1l[16+j] + r1*W1l[32+j] + r2*W1l[48+j];
                atomicMaxNonneg(&agg1[(size_t)c*16+j], fmaxf(v, 0.0f));
            }
        }
    }
    if (tid == 0){ seg1[2*g] = s1; seg1[2*g+1] = n1; }
}

// ================= kernel B: per-glimpse stage 2 =================
// rows [s1,e1): f1 = celu(agg1@W1g+b1g); msg2 = relu([f1,rel]@W2l+b2l); segmax -> agg2; ps2 mean
__global__ __launch_bounds__(256) void kB(const float* __restrict__ ps1,
                                          const float* __restrict__ agg1,
                                          const int* __restrict__ cl2,
                                          const float* __restrict__ W1g,
                                          const float* __restrict__ b1g,
                                          const float* __restrict__ W2l,
                                          const float* __restrict__ b2l,
                                          const int* __restrict__ seg1,
                                          float* __restrict__ ps2,
                                          float* __restrict__ agg2,
                                          float* __restrict__ cnt2,
                                          int* __restrict__ seg2){
    __shared__ float sx[N2CAP], sy[N2CAP], sz[N2CAP], sc[N2CAP];
    __shared__ float sagg[N2CAP*64];
    __shared__ int red[2];
    const int g = blockIdx.x, tid = threadIdx.x;
    const int s1 = seg1[2*g], n1 = seg1[2*g+1], e1 = s1 + n1;

    if (tid == 0){ red[0] = 0x7fffffff; red[1] = -1; }
    __syncthreads();
    int mn = 0x7fffffff, mx = -1;
    for (int m = s1 + tid; m < e1; m += 256){ int c = cl2[m]; mn = min(mn,c); mx = max(mx,c); }
    atomicMin(&red[0], mn); atomicMax(&red[1], mx);
    __syncthreads();
    const int s2 = red[0];
    const int n2 = red[1] - red[0] + 1;
    const bool fast = (n2 <= N2CAP);

    if (fast){
        for (int l = tid; l < n2; l += 256){ sx[l]=0.f; sy[l]=0.f; sz[l]=0.f; sc[l]=0.f; }
        for (int t = tid; t < n2*64; t += 256) sagg[t] = 0.f;
        __syncthreads();
        for (int m = s1 + tid; m < e1; m += 256){
            int c = cl2[m] - s2;
            atomicAdd(&sx[c], ps1[3*m+0]);
            atomicAdd(&sy[c], ps1[3*m+1]);
            atomicAdd(&sz[c], ps1[3*m+2]);
            atomicAdd(&sc[c], 1.0f);
        }
        __syncthreads();
        for (int l = tid; l < n2; l += 256){
            float ic = 1.0f / sc[l];
            sx[l] *= ic; sy[l] *= ic; sz[l] *= ic;
        }
        __syncthreads();
        for (int t = tid; t < n2*3; t += 256){
            int l = t/3, d = t - 3*l;
            ps2[(size_t)s2*3 + t] = (d==0) ? sx[l] : ((d==1) ? sy[l] : sz[l]);
        }
        for (int m = s1 + tid; m < e1; m += 256){
            float a[16];
            const float* ar = agg1 + (size_t)m*16;
            #pragma unroll
            for (int k = 0; k < 16; ++k) a[k] = ar[k];
            float in[35];
            #pragma unroll
            for (int j = 0; j < 32; ++j){
                float v = b1g[j];
                #pragma unroll
                for (int k = 0; k < 16; ++k) v += a[k] * W1g[k*32+j];
                in[j] = celu1(v);
            }
            int c = cl2[m] - s2;
            in[32] = ps1[3*m+0] - sx[c];
            in[33] = ps1[3*m+1] - sy[c];
            in[34] = ps1[3*m+2] - sz[c];
            float* dst = &sagg[c*64];
            for (int j = 0; j < 64; ++j){   // j uniform -> scalar weight loads
                float v = b2l[j];
                #pragma unroll
                for (int k = 0; k < 35; ++k) v += in[k] * W2l[k*64+j];
                atomicMaxNonneg(&dst[j], fmaxf(v, 0.0f));
            }
        }
        __syncthreads();
        float4* a4 = (float4*)(agg2 + (size_t)s2*64);
        const float4* s4 = (const float4*)sagg;
        for (int t = tid; t < n2*16; t += 256) a4[t] = s4[t];
    } else {
        for (int t = tid; t < n2;    t += 256) cnt2[s2+t] = 0.f;
        for (int t = tid; t < n2*3;  t += 256) ps2[(size_t)s2*3+t] = 0.f;
        for (int t = tid; t < n2*64; t += 256) agg2[(size_t)s2*64+t] = 0.f;
        __syncthreads();
        for (int m = s1 + tid; m < e1; m += 256){
            int c = cl2[m];
            atomicAdd(&ps2[3*c+0], ps1[3*m+0]);
            atomicAdd(&ps2[3*c+1], ps1[3*m+1]);
            atomicAdd(&ps2[3*c+2], ps1[3*m+2]);
            atomicAdd(&cnt2[c], 1.0f);
        }
        __syncthreads();
        for (int l = tid; l < n2; l += 256){
            float ic = 1.0f / cnt2[s2+l];
            ps2[(size_t)(s2+l)*3+0] *= ic; ps2[(size_t)(s2+l)*3+1] *= ic; ps2[(size_t)(s2+l)*3+2] *= ic;
        }
        __syncthreads();
        for (int m = s1 + tid; m < e1; m += 256){
            float a[16];
            const float* ar = agg1 + (size_t)m*16;
            #pragma unroll
            for (int k = 0; k < 16; ++k) a[k] = ar[k];
            float in[35];
            #pragma unroll
            for (int j = 0; j < 32; ++j){
                float v = b1g[j];
                #pragma unroll
                for (int k = 0; k < 16; ++k) v += a[k] * W1g[k*32+j];
                in[j] = celu1(v);
            }
            int c = cl2[m];
            in[32] = ps1[3*m+0] - ps2[3*c+0];
            in[33] = ps1[3*m+1] - ps2[3*c+1];
            in[34] = ps1[3*m+2] - ps2[3*c+2];
            for (int j = 0; j < 64; ++j){
                float v = b2l[j];
                #pragma unroll
                for (int k = 0; k < 35; ++k) v += in[k] * W2l[k*64+j];
                atomicMaxNonneg(&agg2[(size_t)c*64+j], fmaxf(v, 0.0f));
            }
        }
    }
    if (tid == 0){ seg2[2*g] = s2; seg2[2*g+1] = n2; }
}

// ================= kernel C: per-glimpse f2 + msg3 + head, fused =================
__global__ __launch_bounds__(256) void kC(const float* __restrict__ agg2,
                                          const float* __restrict__ ps2,
                                          const int* __restrict__ seg2,
                                          const float* __restrict__ W2g,
                                          const float* __restrict__ b2g,
                                          const float* __restrict__ W3l,
                                          const float* __restrict__ b3l,
                                          const float* __restrict__ W3g,
                                          const float* __restrict__ b3g,
                                          const float* __restrict__ Wlin,
                                          const float* __restrict__ blin,
                                          const float* __restrict__ eps,
                                          float* __restrict__ out, int G){
    __shared__ float a2c[CH*64];    // 8 KB: agg2 chunk
    __shared__ float f2c[CH*128];   // 16 KB: f2 chunk
    __shared__ float agg3[128];
    __shared__ float f3s[256];
    const int g = blockIdx.x, tid = threadIdx.x;
    const int s2 = seg2[2*g], n2 = seg2[2*g+1];

    for (int t = tid; t < 128; t += 256) agg3[t] = 0.f;

    const int jg = (tid & 31) * 4;
    const int p  = tid >> 5;           // 0..7
    const float4 bl3 = *(const float4*)&b3l[jg];

    for (int c0 = 0; c0 < n2; c0 += CH){
        int nr = min(CH, n2 - c0);
        __syncthreads();   // protect a2c/f2c from previous chunk's readers
        {   // load agg2 chunk (coalesced float4)
            const float4* src = (const float4*)(agg2 + (size_t)(s2 + c0)*64);
            float4* dst = (float4*)a2c;
            for (int t = tid; t < nr*16; t += 256) dst[t] = src[t];
        }
        __syncthreads();
        // ---- f2 = celu(agg2 @ W2g + b2g): thread = (row p, 4-wide channel group jg)
        for (int r0 = 0; r0 < CH; r0 += 8){
            int r = r0 + p;
            if (r < nr){
                float4 acc = *(const float4*)&b2g[jg];
                const float* ar = &a2c[r*64];
                #pragma unroll 8
                for (int k = 0; k < 64; ++k){
                    float x = ar[k];
                    float4 w = *(const float4*)&W2g[k*128 + jg];
                    acc.x += x*w.x; acc.y += x*w.y; acc.z += x*w.z; acc.w += x*w.w;
                }
                float4 o;
                o.x = celu1(acc.x); o.y = celu1(acc.y); o.z = celu1(acc.z); o.w = celu1(acc.w);
                *(float4*)&f2c[r*128 + jg] = o;
            }
        }
        __syncthreads();
        // ---- msg3 = relu([f2, ps2] @ W3l + b3l), max over rows
        float4 mxv = make_float4(0.f, 0.f, 0.f, 0.f);   // relu >= 0 so 0 merges safely
        for (int r = p; r < nr; r += 8){
            float4 acc = bl3;
            const float* fr = &f2c[r*128];
            #pragma unroll 8
            for (int k = 0; k < 128; ++k){
                float x = fr[k];
                float4 w = *(const float4*)&W3l[k*128 + jg];
                acc.x += x*w.x; acc.y += x*w.y; acc.z += x*w.z; acc.w += x*w.w;
            }
            #pragma unroll
            for (int k = 0; k < 3; ++k){
                float x = ps2[(size_t)(s2 + c0 + r)*3 + k];
                float4 w = *(const float4*)&W3l[(128+k)*128 + jg];
                acc.x += x*w.x; acc.y += x*w.y; acc.z += x*w.z; acc.w += x*w.w;
            }
            mxv.x = fmaxf(mxv.x, fmaxf(acc.x, 0.f));
            mxv.y = fmaxf(mxv.y, fmaxf(acc.y, 0.f));
            mxv.z = fmaxf(mxv.z, fmaxf(acc.z, 0.f));
            mxv.w = fmaxf(mxv.w, fmaxf(acc.w, 0.f));
        }
        atomicMaxNonneg(&agg3[jg+0], mxv.x);
        atomicMaxNonneg(&agg3[jg+1], mxv.y);
        atomicMaxNonneg(&agg3[jg+2], mxv.z);
        atomicMaxNonneg(&agg3[jg+3], mxv.w);
    }
    __syncthreads();

    // ---- head: f3 = celu(agg3 @ W3g + b3g); out = f3 @ Wlin + blin; reparam
    const int j = tid;
    float v = b3g[j];
    for (int k = 0; k < 128; ++k) v += agg3[k] * W3g[k*256 + j];
    v = celu1(v);
    f3s[j] = v;
    const size_t o_zm = (size_t)64*G, o_mu = (size_t)128*G, o_sg = (size_t)256*G, o_f3 = (size_t)384*G;
    out[o_f3 + (size_t)g*256 + j] = v;
    __syncthreads();

    float h = blin[j];
    for (int k = 0; k < 256; ++k) h += f3s[k] * Wlin[k*256 + j];
    __syncthreads();
    f3s[j] = h;          // reuse as h-staging
    __syncthreads();

    if (j < 128){
        float mu = f3s[j];
        float sg = softplus1(f3s[128 + j]);
        float z = mu + sg * eps[(size_t)g*128 + j];
        out[o_mu + (size_t)g*128 + j] = mu;
        out[o_sg + (size_t)g*128 + j] = sg;
        if (j < 64) out[(size_t)g*64 + j] = z;
        else        out[o_zm + (size_t)g*64 + (j - 64)] = z;
    }
}

extern "C" void kernel_launch(void* const* d_in, const int* in_sizes, int n_in,
                              void* d_out, int out_size, void* d_ws, size_t ws_size,
                              hipStream_t stream) {
    const float* rgb  = (const float*)d_in[0];
    const float* pos  = (const float*)d_in[1];
    const float* W1l  = (const float*)d_in[3];
    const float* b1l  = (const float*)d_in[4];
    const float* W1g  = (const float*)d_in[5];
    const float* b1g  = (const float*)d_in[6];
    const float* W2l  = (const float*)d_in[7];
    const float* b2l  = (const float*)d_in[8];
    const float* W2g  = (const float*)d_in[9];
    const float* b2g  = (const float*)d_in[10];
    const float* W3l  = (const float*)d_in[11];
    const float* b3l  = (const float*)d_in[12];
    const float* W3g  = (const float*)d_in[13];
    const float* b3g  = (const float*)d_in[14];
    const float* Wlin = (const float*)d_in[15];
    const float* blin = (const float*)d_in[16];
    const float* eps  = (const float*)d_in[17];
    const int* cl1 = (const int*)d_in[19];
    const int* cl2 = (const int*)d_in[20];
    const int* b2i = (const int*)d_in[21]; (void)b2i;

    const int N  = in_sizes[19];
    const int G  = in_sizes[17] / 128;
    const int M1 = in_sizes[20];
    const int M2 = in_sizes[21];
    const int P  = N / G;

    char* ws = (char*)d_ws;
    auto al = [](size_t x){ return (x + 255) & ~(size_t)255; };
    size_t off = 0;
    float* ps1  = (float*)(ws + off); off = al(off + 12ull*M1);
    float* agg1 = (float*)(ws + off); off = al(off + 64ull*M1);
    float* cnt1 = (float*)(ws + off); off = al(off + 4ull*M1);
    float* ps2  = (float*)(ws + off); off = al(off + 12ull*M2);
    float* agg2 = (float*)(ws + off); off = al(off + 256ull*M2);
    float* cnt2 = (float*)(ws + off); off = al(off + 4ull*M2);
    int*   seg1 = (int*)  (ws + off); off = al(off + 8ull*G);
    int*   seg2 = (int*)  (ws + off); off = al(off + 8ull*G);
    if (off > ws_size) return;

    kA<<<G, 256, 0, stream>>>(rgb, pos, cl1, W1l, b1l, ps1, agg1, cnt1, seg1, P);
    kB<<<G, 256, 0, stream>>>(ps1, agg1, cl2, W1g, b1g, W2l, b2l, seg1, ps2, agg2, cnt2, seg2);
    kC<<<G, 256, 0, stream>>>(agg2, ps2, seg2, W2g, b2g, W3l, b3l, W3g, b3g, Wlin, blin, eps,
                              (float*)d_out, G);
}

// Round 4
// 517.982 us; speedup vs baseline: 6.8241x; 1.1481x over previous
//
#include <hip/hip_runtime.h>
#include <math.h>

#define N1CAP 736
#define N2CAP 224
#define S3 132   // padded row-stride for transposed x tiles (multiple of 4, not mult of 32)

__device__ __forceinline__ float celu1(float x){ return x > 0.f ? x : (expf(x) - 1.f); }
__device__ __forceinline__ float softplus1(float x){ return fmaxf(x, 0.f) + log1pf(expf(-fabsf(x))); }
// valid only for v >= 0 with zero-initialized destination (works on LDS or global pointers)
__device__ __forceinline__ void atomicMaxNonneg(float* p, float v){
    atomicMax((int*)p, __float_as_int(v));
}

// ================= kernel A: per-glimpse stage 1 =================
__global__ __launch_bounds__(256) void kA(const float* __restrict__ rgb,
                                          const float* __restrict__ pos,
                                          const int* __restrict__ cl1,
                                          const float* __restrict__ W1l,
                                          const float* __restrict__ b1l,
                                          float* __restrict__ ps1,
                                          float* __restrict__ agg1,
                                          float* __restrict__ cnt1,
                                          int* __restrict__ seg1, int P){
    __shared__ float shx[N1CAP], shy[N1CAP], shz[N1CAP], shc[N1CAP];
    __shared__ float sha[N1CAP*17];    // stride 17: atomic bank = (17c+j)%32 spreads over c
    __shared__ int red[2];
    const int g = blockIdx.x, tid = threadIdx.x;
    const int base = g * P;

    if (tid == 0){ red[0] = 0x7fffffff; red[1] = -1; }
    __syncthreads();
    int mn = 0x7fffffff, mx = -1;
    for (int i = tid; i < P; i += 256){ int c = cl1[base+i]; mn = min(mn,c); mx = max(mx,c); }
    atomicMin(&red[0], mn); atomicMax(&red[1], mx);
    __syncthreads();
    const int s1 = red[0];
    const int n1 = red[1] - red[0] + 1;
    const bool fast = (n1 <= N1CAP);

    if (fast){
        for (int l = tid; l < n1; l += 256){ shx[l]=0.f; shy[l]=0.f; shz[l]=0.f; shc[l]=0.f; }
        for (int t = tid; t < n1*17; t += 256) sha[t] = 0.f;
        __syncthreads();
        for (int i = tid; i < P; i += 256){
            int idx = base + i; int c = cl1[idx] - s1;
            atomicAdd(&shx[c], pos[3*idx+0]);
            atomicAdd(&shy[c], pos[3*idx+1]);
            atomicAdd(&shz[c], pos[3*idx+2]);
            atomicAdd(&shc[c], 1.0f);
        }
        __syncthreads();
        for (int l = tid; l < n1; l += 256){
            float ic = 1.0f / shc[l];
            shx[l] *= ic; shy[l] *= ic; shz[l] *= ic;
        }
        __syncthreads();
        for (int i = tid; i < P; i += 256){
            int idx = base + i; int c = cl1[idx] - s1;
            float in0 = rgb[idx];
            float r0 = pos[3*idx+0] - shx[c];
            float r1 = pos[3*idx+1] - shy[c];
            float r2 = pos[3*idx+2] - shz[c];
            float* dst = &sha[c*17];
            #pragma unroll
            for (int j = 0; j < 16; ++j){
                float v = b1l[j] + in0*W1l[j] + r0*W1l[16+j] + r1*W1l[32+j] + r2*W1l[48+j];
                atomicMaxNonneg(&dst[j], fmaxf(v, 0.0f));
            }
        }
        __syncthreads();
        for (int t = tid; t < n1*3; t += 256){
            int l = t/3, d = t - 3*l;
            ps1[(size_t)s1*3 + t] = (d==0) ? shx[l] : ((d==1) ? shy[l] : shz[l]);
        }
        for (int t = tid; t < n1*16; t += 256){
            int l = t >> 4, j = t & 15;
            agg1[(size_t)s1*16 + t] = sha[l*17 + j];
        }
    } else {
        for (int t = tid; t < n1;    t += 256) cnt1[s1+t] = 0.f;
        for (int t = tid; t < n1*3;  t += 256) ps1[(size_t)s1*3+t] = 0.f;
        for (int t = tid; t < n1*16; t += 256) agg1[(size_t)s1*16+t] = 0.f;
        __syncthreads();
        for (int i = tid; i < P; i += 256){
            int idx = base + i; int c = cl1[idx];
            atomicAdd(&ps1[3*c+0], pos[3*idx+0]);
            atomicAdd(&ps1[3*c+1], pos[3*idx+1]);
            atomicAdd(&ps1[3*c+2], pos[3*idx+2]);
            atomicAdd(&cnt1[c], 1.0f);
        }
        __syncthreads();
        for (int l = tid; l < n1; l += 256){
            float ic = 1.0f / cnt1[s1+l];
            ps1[(size_t)(s1+l)*3+0] *= ic; ps1[(size_t)(s1+l)*3+1] *= ic; ps1[(size_t)(s1+l)*3+2] *= ic;
        }
        __syncthreads();
        for (int i = tid; i < P; i += 256){
            int idx = base + i; int c = cl1[idx];
            float in0 = rgb[idx];
            float r0 = pos[3*idx+0] - ps1[3*c+0];
            float r1 = pos[3*idx+1] - ps1[3*c+1];
            float r2 = pos[3*idx+2] - ps1[3*c+2];
            #pragma unroll
            for (int j = 0; j < 16; ++j){
                float v = b1l[j] + in0*W1l[j] + r0*W1l[16+j] + r1*W1l[32+j] + r2*W1l[48+j];
                atomicMaxNonneg(&agg1[(size_t)c*16+j], fmaxf(v, 0.0f));
            }
        }
    }
    if (tid == 0){ seg1[2*g] = s1; seg1[2*g+1] = n1; }
}

// ================= kernel B: per-glimpse stage 2 =================
__global__ __launch_bounds__(256) void kB(const float* __restrict__ ps1,
                                          const float* __restrict__ agg1,
                                          const int* __restrict__ cl2,
                                          const float* __restrict__ W1g,
                                          const float* __restrict__ b1g,
                                          const float* __restrict__ W2l,
                                          const float* __restrict__ b2l,
                                          const int* __restrict__ seg1,
                                          float* __restrict__ ps2,
                                          float* __restrict__ agg2,
                                          float* __restrict__ cnt2){
    __shared__ float sx[N2CAP], sy[N2CAP], sz[N2CAP], sc[N2CAP];
    __shared__ float sagg[N2CAP*65];   // stride 65: atomic bank = (65c+j)%32 = (c+j)%32 spreads
    __shared__ int red[2];
    const int g = blockIdx.x, tid = threadIdx.x;
    const int s1 = seg1[2*g], n1 = seg1[2*g+1], e1 = s1 + n1;

    if (tid == 0){ red[0] = 0x7fffffff; red[1] = -1; }
    __syncthreads();
    int mn = 0x7fffffff, mx = -1;
    for (int m = s1 + tid; m < e1; m += 256){ int c = cl2[m]; mn = min(mn,c); mx = max(mx,c); }
    atomicMin(&red[0], mn); atomicMax(&red[1], mx);
    __syncthreads();
    const int s2 = red[0];
    const int n2 = red[1] - red[0] + 1;
    const bool fast = (n2 <= N2CAP);

    if (fast){
        for (int l = tid; l < n2; l += 256){ sx[l]=0.f; sy[l]=0.f; sz[l]=0.f; sc[l]=0.f; }
        for (int t = tid; t < n2*65; t += 256) sagg[t] = 0.f;
        __syncthreads();
        for (int m = s1 + tid; m < e1; m += 256){
            int c = cl2[m] - s2;
            atomicAdd(&sx[c], ps1[3*m+0]);
            atomicAdd(&sy[c], ps1[3*m+1]);
            atomicAdd(&sz[c], ps1[3*m+2]);
            atomicAdd(&sc[c], 1.0f);
        }
        __syncthreads();
        for (int l = tid; l < n2; l += 256){
            float ic = 1.0f / sc[l];
            sx[l] *= ic; sy[l] *= ic; sz[l] *= ic;
        }
        __syncthreads();
        for (int t = tid; t < n2*3; t += 256){
            int l = t/3, d = t - 3*l;
            ps2[(size_t)s2*3 + t] = (d==0) ? sx[l] : ((d==1) ? sy[l] : sz[l]);
        }
        for (int m = s1 + tid; m < e1; m += 256){
            float a[16];
            const float* ar = agg1 + (size_t)m*16;
            #pragma unroll
            for (int k = 0; k < 16; ++k) a[k] = ar[k];
            float in[35];
            #pragma unroll
            for (int j = 0; j < 32; ++j){
                float v = b1g[j];
                #pragma unroll
                for (int k = 0; k < 16; ++k) v += a[k] * W1g[k*32+j];
                in[j] = celu1(v);
            }
            int c = cl2[m] - s2;
            in[32] = ps1[3*m+0] - sx[c];
            in[33] = ps1[3*m+1] - sy[c];
            in[34] = ps1[3*m+2] - sz[c];
            float* dst = &sagg[c*65];
            for (int j = 0; j < 64; ++j){
                float v = b2l[j];
                #pragma unroll
                for (int k = 0; k < 35; ++k) v += in[k] * W2l[k*64+j];
                atomicMaxNonneg(&dst[j], fmaxf(v, 0.0f));
            }
        }
        __syncthreads();
        for (int t = tid; t < n2*64; t += 256){
            int l = t >> 6, j = t & 63;
            agg2[(size_t)s2*64 + t] = sagg[l*65 + j];
        }
    } else {
        for (int t = tid; t < n2;    t += 256) cnt2[s2+t] = 0.f;
        for (int t = tid; t < n2*3;  t += 256) ps2[(size_t)s2*3+t] = 0.f;
        for (int t = tid; t < n2*64; t += 256) agg2[(size_t)s2*64+t] = 0.f;
        __syncthreads();
        for (int m = s1 + tid; m < e1; m += 256){
            int c = cl2[m];
            atomicAdd(&ps2[3*c+0], ps1[3*m+0]);
            atomicAdd(&ps2[3*c+1], ps1[3*m+1]);
            atomicAdd(&ps2[3*c+2], ps1[3*m+2]);
            atomicAdd(&cnt2[c], 1.0f);
        }
        __syncthreads();
        for (int l = tid; l < n2; l += 256){
            float ic = 1.0f / cnt2[s2+l];
            ps2[(size_t)(s2+l)*3+0] *= ic; ps2[(size_t)(s2+l)*3+1] *= ic; ps2[(size_t)(s2+l)*3+2] *= ic;
        }
        __syncthreads();
        for (int m = s1 + tid; m < e1; m += 256){
            float a[16];
            const float* ar = agg1 + (size_t)m*16;
            #pragma unroll
            for (int k = 0; k < 16; ++k) a[k] = ar[k];
            float in[35];
            #pragma unroll
            for (int j = 0; j < 32; ++j){
                float v = b1g[j];
                #pragma unroll
                for (int k = 0; k < 16; ++k) v += a[k] * W1g[k*32+j];
                in[j] = celu1(v);
            }
            int c = cl2[m];
            in[32] = ps1[3*m+0] - ps2[3*c+0];
            in[33] = ps1[3*m+1] - ps2[3*c+1];
            in[34] = ps1[3*m+2] - ps2[3*c+2];
            for (int j = 0; j < 64; ++j){
                float v = b2l[j];
                #pragma unroll
                for (int k = 0; k < 35; ++k) v += in[k] * W2l[k*64+j];
                atomicMaxNonneg(&agg2[(size_t)c*64+j], fmaxf(v, 0.0f));
            }
        }
    }
}

// ================= flat GEMM: f2 = celu(agg2[M2x64] @ W2g + b2g) =================
// block = 128 rows; 256 thr = 32 row-groups(x4) x 8 ch-groups(x16)
__global__ __launch_bounds__(256) void k_f2f(const float* __restrict__ agg2,
                                             const float* __restrict__ W2g,
                                             const float* __restrict__ b2g,
                                             float* __restrict__ f2, int M2){
    __shared__ float Ws[64*128];   // 32 KB, [k][128]
    __shared__ float xt[32*S3];    // 16.9 KB, [kk][row] transposed
    const int tid = threadIdx.x;
    const int m0 = blockIdx.x * 128;
    for (int t = tid; t < 64*128; t += 256) Ws[t] = W2g[t];
    const int tr = tid & 31, tc = tid >> 5;
    float acc[4][16];
    #pragma unroll
    for (int c = 0; c < 16; ++c){
        float b = b2g[tc*16 + c];
        #pragma unroll
        for (int r = 0; r < 4; ++r) acc[r][c] = b;
    }
    for (int c0 = 0; c0 < 64; c0 += 32){
        __syncthreads();
        for (int t = tid; t < 128*8; t += 256){
            int row = t >> 3, kq = t & 7;
            int m = m0 + row;
            float4 v = (m < M2) ? *(const float4*)&agg2[(size_t)m*64 + c0 + kq*4]
                                : make_float4(0.f,0.f,0.f,0.f);
            xt[(kq*4+0)*S3 + row] = v.x;
            xt[(kq*4+1)*S3 + row] = v.y;
            xt[(kq*4+2)*S3 + row] = v.z;
            xt[(kq*4+3)*S3 + row] = v.w;
        }
        __syncthreads();
        #pragma unroll 4
        for (int kk = 0; kk < 32; ++kk){
            int k = c0 + kk;
            float4 xr = *(const float4*)&xt[kk*S3 + tr*4];
            float xv[4] = {xr.x, xr.y, xr.z, xr.w};
            float wv[16];
            #pragma unroll
            for (int q = 0; q < 4; ++q){
                float4 w = *(const float4*)&Ws[k*128 + tc*16 + q*4];
                wv[q*4+0]=w.x; wv[q*4+1]=w.y; wv[q*4+2]=w.z; wv[q*4+3]=w.w;
            }
            #pragma unroll
            for (int r = 0; r < 4; ++r)
                #pragma unroll
                for (int c = 0; c < 16; ++c) acc[r][c] += xv[r]*wv[c];
        }
    }
    #pragma unroll
    for (int r = 0; r < 4; ++r){
        int m = m0 + tr*4 + r;
        if (m < M2){
            #pragma unroll
            for (int q = 0; q < 4; ++q){
                float4 o;
                o.x = celu1(acc[r][q*4+0]); o.y = celu1(acc[r][q*4+1]);
                o.z = celu1(acc[r][q*4+2]); o.w = celu1(acc[r][q*4+3]);
                *(float4*)&f2[(size_t)m*128 + tc*16 + q*4] = o;
            }
        }
    }
}

// ================= flat GEMM + segmax: msg = relu([f2,ps2][M2x131] @ W3l + b3l) =================
// grid = (ceil(M2/128), 2 ch-halves); 256 thr = 32 row-groups(x4) x 8 ch-groups(x8)
__global__ __launch_bounds__(256) void k_msg3f(const float* __restrict__ f2,
                                               const float* __restrict__ ps2,
                                               const int* __restrict__ b2i,
                                               const float* __restrict__ W3l,
                                               const float* __restrict__ b3l,
                                               float* __restrict__ agg3, int M2){
    __shared__ float Wh[131*64];   // 33.5 KB, [k][64] column half
    __shared__ float xt[32*S3];    // 16.9 KB
    const int tid = threadIdx.x;
    const int cb = blockIdx.y * 64;
    const int m0 = blockIdx.x * 128;
    for (int t = tid; t < 131*64; t += 256){
        int k = t >> 6, c = t & 63;
        Wh[t] = W3l[k*128 + cb + c];
    }
    const int tr = tid & 31, tc = tid >> 5;
    float acc[4][8];
    #pragma unroll
    for (int c = 0; c < 8; ++c){
        float b = b3l[cb + tc*8 + c];
        #pragma unroll
        for (int r = 0; r < 4; ++r) acc[r][c] = b;
    }
    for (int c0 = 0; c0 < 128; c0 += 32){
        __syncthreads();
        for (int t = tid; t < 128*8; t += 256){
            int row = t >> 3, kq = t & 7;
            int m = m0 + row;
            float4 v = (m < M2) ? *(const float4*)&f2[(size_t)m*128 + c0 + kq*4]
                                : make_float4(0.f,0.f,0.f,0.f);
            xt[(kq*4+0)*S3 + row] = v.x;
            xt[(kq*4+1)*S3 + row] = v.y;
            xt[(kq*4+2)*S3 + row] = v.z;
            xt[(kq*4+3)*S3 + row] = v.w;
        }
        __syncthreads();
        #pragma unroll 8
        for (int kk = 0; kk < 32; ++kk){
            int k = c0 + kk;
            float4 xr = *(const float4*)&xt[kk*S3 + tr*4];
            float xv[4] = {xr.x, xr.y, xr.z, xr.w};
            float4 w0 = *(const float4*)&Wh[k*64 + tc*8];
            float4 w1 = *(const float4*)&Wh[k*64 + tc*8 + 4];
            float wv[8] = {w0.x,w0.y,w0.z,w0.w, w1.x,w1.y,w1.z,w1.w};
            #pragma unroll
            for (int r = 0; r < 4; ++r)
                #pragma unroll
                for (int c = 0; c < 8; ++c) acc[r][c] += xv[r]*wv[c];
        }
    }
    // ps2 rows (k = 128..130)
    #pragma unroll
    for (int kk = 0; kk < 3; ++kk){
        const float* w = &Wh[(128+kk)*64 + tc*8];
        float wv[8];
        #pragma unroll
        for (int c = 0; c < 8; ++c) wv[c] = w[c];
        #pragma unroll
        for (int r = 0; r < 4; ++r){
            int m = m0 + tr*4 + r;
            float x = (m < M2) ? ps2[(size_t)m*3 + kk] : 0.f;
            #pragma unroll
            for (int c = 0; c < 8; ++c) acc[r][c] += x*wv[c];
        }
    }
    // relu + run-merge over this thread's 4 consecutive rows, then global atomicMax
    float mx[8];
    int cur_g = -1;
    for (int r = 0; r < 4; ++r){
        int m = m0 + tr*4 + r;
        if (m >= M2) break;
        int g = b2i[m];
        if (g != cur_g){
            if (cur_g >= 0){
                #pragma unroll
                for (int c = 0; c < 8; ++c)
                    atomicMaxNonneg(&agg3[(size_t)cur_g*128 + cb + tc*8 + c], mx[c]);
            }
            cur_g = g;
            #pragma unroll
            for (int c = 0; c < 8; ++c) mx[c] = fmaxf(acc[r][c], 0.f);
        } else {
            #pragma unroll
            for (int c = 0; c < 8; ++c) mx[c] = fmaxf(mx[c], fmaxf(acc[r][c], 0.f));
        }
    }
    if (cur_g >= 0){
        #pragma unroll
        for (int c = 0; c < 8; ++c)
            atomicMaxNonneg(&agg3[(size_t)cur_g*128 + cb + tc*8 + c], mx[c]);
    }
}

// ================= head =================
__global__ __launch_bounds__(256) void k_head(const float* __restrict__ agg3,
                                              const float* __restrict__ W3g,
                                              const float* __restrict__ b3g,
                                              const float* __restrict__ Wlin,
                                              const float* __restrict__ blin,
                                              const float* __restrict__ eps,
                                              float* __restrict__ out, int G){
    __shared__ float a3[128];
    __shared__ float f3s[256];
    __shared__ float hs[256];
    int g = blockIdx.x;
    int j = threadIdx.x;
    if (j < 128) a3[j] = agg3[(size_t)g*128 + j];
    __syncthreads();

    float v = b3g[j];
    for (int k = 0; k < 128; ++k) v += a3[k] * W3g[k*256 + j];
    v = celu1(v);
    f3s[j] = v;
    const size_t o_zm = (size_t)64*G, o_mu = (size_t)128*G, o_sg = (size_t)256*G, o_f3 = (size_t)384*G;
    out[o_f3 + (size_t)g*256 + j] = v;
    __syncthreads();

    float h = blin[j];
    for (int k = 0; k < 256; ++k) h += f3s[k] * Wlin[k*256 + j];
    hs[j] = h;
    __syncthreads();

    if (j < 128){
        float mu = hs[j];
        float sg = softplus1(hs[128 + j]);
        float z = mu + sg * eps[(size_t)g*128 + j];
        out[o_mu + (size_t)g*128 + j] = mu;
        out[o_sg + (size_t)g*128 + j] = sg;
        if (j < 64) out[(size_t)g*64 + j] = z;
        else        out[o_zm + (size_t)g*64 + (j - 64)] = z;
    }
}

extern "C" void kernel_launch(void* const* d_in, const int* in_sizes, int n_in,
                              void* d_out, int out_size, void* d_ws, size_t ws_size,
                              hipStream_t stream) {
    const float* rgb  = (const float*)d_in[0];
    const float* pos  = (const float*)d_in[1];
    const float* W1l  = (const float*)d_in[3];
    const float* b1l  = (const float*)d_in[4];
    const float* W1g  = (const float*)d_in[5];
    const float* b1g  = (const float*)d_in[6];
    const float* W2l  = (const float*)d_in[7];
    const float* b2l  = (const float*)d_in[8];
    const float* W2g  = (const float*)d_in[9];
    const float* b2g  = (const float*)d_in[10];
    const float* W3l  = (const float*)d_in[11];
    const float* b3l  = (const float*)d_in[12];
    const float* W3g  = (const float*)d_in[13];
    const float* b3g  = (const float*)d_in[14];
    const float* Wlin = (const float*)d_in[15];
    const float* blin = (const float*)d_in[16];
    const float* eps  = (const float*)d_in[17];
    const int* cl1 = (const int*)d_in[19];
    const int* cl2 = (const int*)d_in[20];
    const int* b2i = (const int*)d_in[21];

    const int N  = in_sizes[19];
    const int G  = in_sizes[17] / 128;
    const int M1 = in_sizes[20];
    const int M2 = in_sizes[21];
    const int P  = N / G;

    char* ws = (char*)d_ws;
    auto al = [](size_t x){ return (x + 255) & ~(size_t)255; };
    size_t off = 0;
    float* ps1  = (float*)(ws + off); off = al(off + 12ull*M1);
    size_t uni  = ((size_t)64*M1 > (size_t)512*M2) ? (size_t)64*M1 : (size_t)512*M2;
    float* agg1 = (float*)(ws + off);      // agg1 [M1x16] ... later f2 [M2x128] (disjoint lifetimes)
    float* f2   = (float*)(ws + off);
    off = al(off + uni);
    float* cnt1 = (float*)(ws + off); off = al(off + 4ull*M1);
    float* ps2  = (float*)(ws + off); off = al(off + 12ull*M2);
    float* agg2 = (float*)(ws + off); off = al(off + 256ull*M2);
    float* cnt2 = (float*)(ws + off); off = al(off + 4ull*M2);
    float* agg3 = (float*)(ws + off); off = al(off + 512ull*G);
    int*   seg1 = (int*)  (ws + off); off = al(off + 8ull*G);
    if (off > ws_size) return;

    hipMemsetAsync(agg3, 0, 512ull*G, stream);   // segmax destination must start at 0

    kA<<<G, 256, 0, stream>>>(rgb, pos, cl1, W1l, b1l, ps1, agg1, cnt1, seg1, P);
    kB<<<G, 256, 0, stream>>>(ps1, agg1, cl2, W1g, b1g, W2l, b2l, seg1, ps2, agg2, cnt2);
    int gx = (M2 + 127) / 128;
    k_f2f  <<<gx, 256, 0, stream>>>(agg2, W2g, b2g, f2, M2);
    dim3 g3(gx, 2);
    k_msg3f<<<g3, 256, 0, stream>>>(f2, ps2, b2i, W3l, b3l, agg3, M2);
    k_head <<<G, 256, 0, stream>>>(agg3, W3g, b3g, Wlin, blin, eps, (float*)d_out, G);
}

// Round 5
// 423.971 us; speedup vs baseline: 8.3373x; 1.2217x over previous
//
#include <hip/hip_runtime.h>
#include <math.h>

#define N1CAP 736
#define N2CAP 192
#define S3 132   // padded row-stride for transposed x tiles

__device__ __forceinline__ float celu1(float x){ return x > 0.f ? x : (expf(x) - 1.f); }
__device__ __forceinline__ float softplus1(float x){ return fmaxf(x, 0.f) + log1pf(expf(-fabsf(x))); }
// valid only for v >= 0 with zero-initialized destination (works on LDS or global pointers)
__device__ __forceinline__ void atomicMaxNonneg(float* p, float v){
    atomicMax((int*)p, __float_as_int(v));
}

// ================= kernel A: per-glimpse stage 1 =================
// LDS 58.9 KB -> 2 blocks/CU. XOR swizzle (j+c)&15 spreads atomic banks with no pad.
__global__ __launch_bounds__(256) void kA(const float* __restrict__ rgb,
                                          const float* __restrict__ pos,
                                          const int* __restrict__ cl1,
                                          const float* __restrict__ W1l,
                                          const float* __restrict__ b1l,
                                          float* __restrict__ ps1,
                                          float* __restrict__ agg1,
                                          float* __restrict__ cnt1,
                                          int* __restrict__ seg1, int P){
    __shared__ float shx[N1CAP], shy[N1CAP], shz[N1CAP], shc[N1CAP];
    __shared__ float sha[N1CAP*16];
    __shared__ int red[2];
    const int g = blockIdx.x, tid = threadIdx.x;
    const int base = g * P;

    if (tid == 0){ red[0] = 0x7fffffff; red[1] = -1; }
    __syncthreads();
    int mn = 0x7fffffff, mx = -1;
    for (int i = tid; i < P; i += 256){ int c = cl1[base+i]; mn = min(mn,c); mx = max(mx,c); }
    atomicMin(&red[0], mn); atomicMax(&red[1], mx);
    __syncthreads();
    const int s1 = red[0];
    const int n1 = red[1] - red[0] + 1;
    const bool fast = (n1 <= N1CAP);

    if (fast){
        for (int l = tid; l < n1; l += 256){ shx[l]=0.f; shy[l]=0.f; shz[l]=0.f; shc[l]=0.f; }
        for (int t = tid; t < n1*16; t += 256) sha[t] = 0.f;
        __syncthreads();
        for (int i = tid; i < P; i += 256){
            int idx = base + i; int c = cl1[idx] - s1;
            atomicAdd(&shx[c], pos[3*idx+0]);
            atomicAdd(&shy[c], pos[3*idx+1]);
            atomicAdd(&shz[c], pos[3*idx+2]);
            atomicAdd(&shc[c], 1.0f);
        }
        __syncthreads();
        for (int l = tid; l < n1; l += 256){
            float ic = 1.0f / shc[l];
            shx[l] *= ic; shy[l] *= ic; shz[l] *= ic;
        }
        __syncthreads();
        for (int i = tid; i < P; i += 256){
            int idx = base + i; int c = cl1[idx] - s1;
            float in0 = rgb[idx];
            float r0 = pos[3*idx+0] - shx[c];
            float r1 = pos[3*idx+1] - shy[c];
            float r2 = pos[3*idx+2] - shz[c];
            float* dst = &sha[c*16];
            #pragma unroll
            for (int j = 0; j < 16; ++j){
                float v = b1l[j] + in0*W1l[j] + r0*W1l[16+j] + r1*W1l[32+j] + r2*W1l[48+j];
                atomicMaxNonneg(&dst[(j + c) & 15], fmaxf(v, 0.0f));
            }
        }
        __syncthreads();
        for (int t = tid; t < n1*3; t += 256){
            int l = t/3, d = t - 3*l;
            ps1[(size_t)s1*3 + t] = (d==0) ? shx[l] : ((d==1) ? shy[l] : shz[l]);
        }
        for (int t = tid; t < n1*16; t += 256){
            int l = t >> 4, j = t & 15;
            agg1[(size_t)s1*16 + t] = sha[l*16 + ((j + l) & 15)];
        }
    } else {
        for (int t = tid; t < n1;    t += 256) cnt1[s1+t] = 0.f;
        for (int t = tid; t < n1*3;  t += 256) ps1[(size_t)s1*3+t] = 0.f;
        for (int t = tid; t < n1*16; t += 256) agg1[(size_t)s1*16+t] = 0.f;
        __syncthreads();
        for (int i = tid; i < P; i += 256){
            int idx = base + i; int c = cl1[idx];
            atomicAdd(&ps1[3*c+0], pos[3*idx+0]);
            atomicAdd(&ps1[3*c+1], pos[3*idx+1]);
            atomicAdd(&ps1[3*c+2], pos[3*idx+2]);
            atomicAdd(&cnt1[c], 1.0f);
        }
        __syncthreads();
        for (int l = tid; l < n1; l += 256){
            float ic = 1.0f / cnt1[s1+l];
            ps1[(size_t)(s1+l)*3+0] *= ic; ps1[(size_t)(s1+l)*3+1] *= ic; ps1[(size_t)(s1+l)*3+2] *= ic;
        }
        __syncthreads();
        for (int i = tid; i < P; i += 256){
            int idx = base + i; int c = cl1[idx];
            float in0 = rgb[idx];
            float r0 = pos[3*idx+0] - ps1[3*c+0];
            float r1 = pos[3*idx+1] - ps1[3*c+1];
            float r2 = pos[3*idx+2] - ps1[3*c+2];
            #pragma unroll
            for (int j = 0; j < 16; ++j){
                float v = b1l[j] + in0*W1l[j] + r0*W1l[16+j] + r1*W1l[32+j] + r2*W1l[48+j];
                atomicMaxNonneg(&agg1[(size_t)c*16+j], fmaxf(v, 0.0f));
            }
        }
    }
    if (tid == 0){ seg1[2*g] = s1; seg1[2*g+1] = n1; }
}

// ================= kernel B: per-glimpse stage 2 =================
// LDS 52.2 KB -> 3 blocks/CU. XOR swizzle (j+c)&63.
__global__ __launch_bounds__(256) void kB(const float* __restrict__ ps1,
                                          const float* __restrict__ agg1,
                                          const int* __restrict__ cl2,
                                          const float* __restrict__ W1g,
                                          const float* __restrict__ b1g,
                                          const float* __restrict__ W2l,
                                          const float* __restrict__ b2l,
                                          const int* __restrict__ seg1,
                                          float* __restrict__ ps2,
                                          float* __restrict__ agg2,
                                          float* __restrict__ cnt2,
                                          int* __restrict__ seg2){
    __shared__ float sx[N2CAP], sy[N2CAP], sz[N2CAP], sc[N2CAP];
    __shared__ float sagg[N2CAP*64];
    __shared__ int red[2];
    const int g = blockIdx.x, tid = threadIdx.x;
    const int s1 = seg1[2*g], n1 = seg1[2*g+1], e1 = s1 + n1;

    if (tid == 0){ red[0] = 0x7fffffff; red[1] = -1; }
    __syncthreads();
    int mn = 0x7fffffff, mx = -1;
    for (int m = s1 + tid; m < e1; m += 256){ int c = cl2[m]; mn = min(mn,c); mx = max(mx,c); }
    atomicMin(&red[0], mn); atomicMax(&red[1], mx);
    __syncthreads();
    const int s2 = red[0];
    const int n2 = red[1] - red[0] + 1;
    const bool fast = (n2 <= N2CAP);

    if (fast){
        for (int l = tid; l < n2; l += 256){ sx[l]=0.f; sy[l]=0.f; sz[l]=0.f; sc[l]=0.f; }
        for (int t = tid; t < n2*64; t += 256) sagg[t] = 0.f;
        __syncthreads();
        for (int m = s1 + tid; m < e1; m += 256){
            int c = cl2[m] - s2;
            atomicAdd(&sx[c], ps1[3*m+0]);
            atomicAdd(&sy[c], ps1[3*m+1]);
            atomicAdd(&sz[c], ps1[3*m+2]);
            atomicAdd(&sc[c], 1.0f);
        }
        __syncthreads();
        for (int l = tid; l < n2; l += 256){
            float ic = 1.0f / sc[l];
            sx[l] *= ic; sy[l] *= ic; sz[l] *= ic;
        }
        __syncthreads();
        for (int t = tid; t < n2*3; t += 256){
            int l = t/3, d = t - 3*l;
            ps2[(size_t)s2*3 + t] = (d==0) ? sx[l] : ((d==1) ? sy[l] : sz[l]);
        }
        for (int m = s1 + tid; m < e1; m += 256){
            float a[16];
            const float* ar = agg1 + (size_t)m*16;
            #pragma unroll
            for (int k = 0; k < 16; ++k) a[k] = ar[k];
            float in[35];
            #pragma unroll
            for (int j = 0; j < 32; ++j){
                float v = b1g[j];
                #pragma unroll
                for (int k = 0; k < 16; ++k) v += a[k] * W1g[k*32+j];
                in[j] = celu1(v);
            }
            int c = cl2[m] - s2;
            in[32] = ps1[3*m+0] - sx[c];
            in[33] = ps1[3*m+1] - sy[c];
            in[34] = ps1[3*m+2] - sz[c];
            float* dst = &sagg[c*64];
            for (int j = 0; j < 64; ++j){
                float v = b2l[j];
                #pragma unroll
                for (int k = 0; k < 35; ++k) v += in[k] * W2l[k*64+j];
                atomicMaxNonneg(&dst[(j + c) & 63], fmaxf(v, 0.0f));
            }
        }
        __syncthreads();
        for (int t = tid; t < n2*64; t += 256){
            int l = t >> 6, j = t & 63;
            agg2[(size_t)s2*64 + t] = sagg[l*64 + ((j + l) & 63)];
        }
    } else {
        for (int t = tid; t < n2;    t += 256) cnt2[s2+t] = 0.f;
        for (int t = tid; t < n2*3;  t += 256) ps2[(size_t)s2*3+t] = 0.f;
        for (int t = tid; t < n2*64; t += 256) agg2[(size_t)s2*64+t] = 0.f;
        __syncthreads();
        for (int m = s1 + tid; m < e1; m += 256){
            int c = cl2[m];
            atomicAdd(&ps2[3*c+0], ps1[3*m+0]);
            atomicAdd(&ps2[3*c+1], ps1[3*m+1]);
            atomicAdd(&ps2[3*c+2], ps1[3*m+2]);
            atomicAdd(&cnt2[c], 1.0f);
        }
        __syncthreads();
        for (int l = tid; l < n2; l += 256){
            float ic = 1.0f / cnt2[s2+l];
            ps2[(size_t)(s2+l)*3+0] *= ic; ps2[(size_t)(s2+l)*3+1] *= ic; ps2[(size_t)(s2+l)*3+2] *= ic;
        }
        __syncthreads();
        for (int m = s1 + tid; m < e1; m += 256){
            float a[16];
            const float* ar = agg1 + (size_t)m*16;
            #pragma unroll
            for (int k = 0; k < 16; ++k) a[k] = ar[k];
            float in[35];
            #pragma unroll
            for (int j = 0; j < 32; ++j){
                float v = b1g[j];
                #pragma unroll
                for (int k = 0; k < 16; ++k) v += a[k] * W1g[k*32+j];
                in[j] = celu1(v);
            }
            int c = cl2[m];
            in[32] = ps1[3*m+0] - ps2[3*c+0];
            in[33] = ps1[3*m+1] - ps2[3*c+1];
            in[34] = ps1[3*m+2] - ps2[3*c+2];
            for (int j = 0; j < 64; ++j){
                float v = b2l[j];
                #pragma unroll
                for (int k = 0; k < 35; ++k) v += in[k] * W2l[k*64+j];
                atomicMaxNonneg(&agg2[(size_t)c*64+j], fmaxf(v, 0.0f));
            }
        }
    }
    if (tid == 0){ seg2[2*g] = s2; seg2[2*g+1] = n2; }
}

// ================= flat GEMM: f2 = celu(agg2[M2x64] @ W2g + b2g) =================
__global__ __launch_bounds__(256) void k_f2f(const float* __restrict__ agg2,
                                             const float* __restrict__ W2g,
                                             const float* __restrict__ b2g,
                                             float* __restrict__ f2, int M2){
    __shared__ float Ws[64*128];   // 32 KB, [k][128]
    __shared__ float xt[32*S3];    // 16.9 KB
    const int tid = threadIdx.x;
    const int m0 = blockIdx.x * 128;
    for (int t = tid; t < 64*128; t += 256) Ws[t] = W2g[t];
    const int tr = tid & 31, tc = tid >> 5;
    float acc[4][16];
    #pragma unroll
    for (int c = 0; c < 16; ++c){
        float b = b2g[tc*16 + c];
        #pragma unroll
        for (int r = 0; r < 4; ++r) acc[r][c] = b;
    }
    for (int c0 = 0; c0 < 64; c0 += 32){
        __syncthreads();
        for (int t = tid; t < 128*8; t += 256){
            int row = t >> 3, kq = t & 7;
            int m = m0 + row;
            float4 v = (m < M2) ? *(const float4*)&agg2[(size_t)m*64 + c0 + kq*4]
                                : make_float4(0.f,0.f,0.f,0.f);
            xt[(kq*4+0)*S3 + row] = v.x;
            xt[(kq*4+1)*S3 + row] = v.y;
            xt[(kq*4+2)*S3 + row] = v.z;
            xt[(kq*4+3)*S3 + row] = v.w;
        }
        __syncthreads();
        #pragma unroll 4
        for (int kk = 0; kk < 32; ++kk){
            int k = c0 + kk;
            float4 xr = *(const float4*)&xt[kk*S3 + tr*4];
            float xv[4] = {xr.x, xr.y, xr.z, xr.w};
            float wv[16];
            #pragma unroll
            for (int q = 0; q < 4; ++q){
                float4 w = *(const float4*)&Ws[k*128 + tc*16 + q*4];
                wv[q*4+0]=w.x; wv[q*4+1]=w.y; wv[q*4+2]=w.z; wv[q*4+3]=w.w;
            }
            #pragma unroll
            for (int r = 0; r < 4; ++r)
                #pragma unroll
                for (int c = 0; c < 16; ++c) acc[r][c] += xv[r]*wv[c];
        }
    }
    #pragma unroll
    for (int r = 0; r < 4; ++r){
        int m = m0 + tr*4 + r;
        if (m < M2){
            #pragma unroll
            for (int q = 0; q < 4; ++q){
                float4 o;
                o.x = celu1(acc[r][q*4+0]); o.y = celu1(acc[r][q*4+1]);
                o.z = celu1(acc[r][q*4+2]); o.w = celu1(acc[r][q*4+3]);
                *(float4*)&f2[(size_t)m*128 + tc*16 + q*4] = o;
            }
        }
    }
}

// ================= stage-3 GEMM + block-local segmax, ZERO global atomics =================
// block = glimpse pair (2bx, 2bx+1); their rows are contiguous [S, S+T), boundary at B.
// grid.y = channel half. Seg-max into LDS, one plain store per (glimpse, channel).
__global__ __launch_bounds__(256) void k_msg3g(const float* __restrict__ f2,
                                               const float* __restrict__ ps2,
                                               const int* __restrict__ seg2,
                                               const float* __restrict__ W3l,
                                               const float* __restrict__ b3l,
                                               float* __restrict__ agg3, int G){
    __shared__ float Wh[131*64];   // 33.5 KB column half
    __shared__ float xt[32*S3];    // 16.9 KB
    __shared__ float shAgg[128];   // [2 glimpses][64 ch]
    const int tid = threadIdx.x;
    const int cb = blockIdx.y * 64;
    const int g0 = blockIdx.x * 2;
    const int S  = seg2[2*g0];
    const int B  = seg2[2*g0+1];
    const int n2b = (g0 + 1 < G) ? seg2[2*g0+3] : 0;
    const int T  = B + n2b;
    for (int t = tid; t < 131*64; t += 256){
        int k = t >> 6, c = t & 63;
        Wh[t] = W3l[k*128 + cb + c];
    }
    if (tid < 128) shAgg[tid] = 0.f;
    const int tr = tid & 31, tc = tid >> 5;
    float bias[8];
    #pragma unroll
    for (int c = 0; c < 8; ++c) bias[c] = b3l[cb + tc*8 + c];

    for (int w0 = 0; w0 < T; w0 += 128){
        float acc[4][8];
        #pragma unroll
        for (int r = 0; r < 4; ++r)
            #pragma unroll
            for (int c = 0; c < 8; ++c) acc[r][c] = bias[c];
        for (int c0 = 0; c0 < 128; c0 += 32){
            __syncthreads();
            for (int t = tid; t < 128*8; t += 256){
                int row = t >> 3, kq = t & 7;
                int ridx = w0 + row;
                float4 v = (ridx < T) ? *(const float4*)&f2[(size_t)(S+ridx)*128 + c0 + kq*4]
                                      : make_float4(0.f,0.f,0.f,0.f);
                xt[(kq*4+0)*S3 + row] = v.x;
                xt[(kq*4+1)*S3 + row] = v.y;
                xt[(kq*4+2)*S3 + row] = v.z;
                xt[(kq*4+3)*S3 + row] = v.w;
            }
            __syncthreads();
            #pragma unroll 8
            for (int kk = 0; kk < 32; ++kk){
                int k = c0 + kk;
                float4 xr = *(const float4*)&xt[kk*S3 + tr*4];
                float xv[4] = {xr.x, xr.y, xr.z, xr.w};
                float4 wa = *(const float4*)&Wh[k*64 + tc*8];
                float4 wb = *(const float4*)&Wh[k*64 + tc*8 + 4];
                float wv[8] = {wa.x,wa.y,wa.z,wa.w, wb.x,wb.y,wb.z,wb.w};
                #pragma unroll
                for (int r = 0; r < 4; ++r)
                    #pragma unroll
                    for (int c = 0; c < 8; ++c) acc[r][c] += xv[r]*wv[c];
            }
        }
        // ps2 rows (k = 128..130)
        #pragma unroll
        for (int kk = 0; kk < 3; ++kk){
            const float* w = &Wh[(128+kk)*64 + tc*8];
            float wv[8];
            #pragma unroll
            for (int c = 0; c < 8; ++c) wv[c] = w[c];
            #pragma unroll
            for (int r = 0; r < 4; ++r){
                int ridx = w0 + tr*4 + r;
                float x = (ridx < T) ? ps2[(size_t)(S+ridx)*3 + kk] : 0.f;
                #pragma unroll
                for (int c = 0; c < 8; ++c) acc[r][c] += x*wv[c];
            }
        }
        // relu + per-thread max per glimpse, then LDS atomicMax
        float mx0[8], mx1[8];
        #pragma unroll
        for (int c = 0; c < 8; ++c){ mx0[c] = 0.f; mx1[c] = 0.f; }
        bool h0 = false, h1 = false;
        #pragma unroll
        for (int r = 0; r < 4; ++r){
            int ridx = w0 + tr*4 + r;
            if (ridx < T){
                bool second = (ridx >= B);
                h0 |= !second; h1 |= second;
                #pragma unroll
                for (int c = 0; c < 8; ++c){
                    float v = fmaxf(acc[r][c], 0.f);
                    mx0[c] = fmaxf(mx0[c], second ? 0.f : v);
                    mx1[c] = fmaxf(mx1[c], second ? v : 0.f);
                }
            }
        }
        if (h0){
            #pragma unroll
            for (int c = 0; c < 8; ++c) atomicMaxNonneg(&shAgg[tc*8 + c], mx0[c]);
        }
        if (h1){
            #pragma unroll
            for (int c = 0; c < 8; ++c) atomicMaxNonneg(&shAgg[64 + tc*8 + c], mx1[c]);
        }
    }
    __syncthreads();
    if (tid < 128){
        int loc = tid >> 6, c = tid & 63;
        int g = g0 + loc;
        if (loc == 0 || n2b > 0)
            agg3[(size_t)g*128 + cb + c] = shAgg[loc*64 + c];
    }
}

// ================= head =================
__global__ __launch_bounds__(256) void k_head(const float* __restrict__ agg3,
                                              const float* __restrict__ W3g,
                                              const float* __restrict__ b3g,
                                              const float* __restrict__ Wlin,
                                              const float* __restrict__ blin,
                                              const float* __restrict__ eps,
                                              float* __restrict__ out, int G){
    __shared__ float a3[128];
    __shared__ float f3s[256];
    __shared__ float hs[256];
    int g = blockIdx.x;
    int j = threadIdx.x;
    if (j < 128) a3[j] = agg3[(size_t)g*128 + j];
    __syncthreads();

    float v = b3g[j];
    for (int k = 0; k < 128; ++k) v += a3[k] * W3g[k*256 + j];
    v = celu1(v);
    f3s[j] = v;
    const size_t o_zm = (size_t)64*G, o_mu = (size_t)128*G, o_sg = (size_t)256*G, o_f3 = (size_t)384*G;
    out[o_f3 + (size_t)g*256 + j] = v;
    __syncthreads();

    float h = blin[j];
    for (int k = 0; k < 256; ++k) h += f3s[k] * Wlin[k*256 + j];
    hs[j] = h;
    __syncthreads();

    if (j < 128){
        float mu = hs[j];
        float sg = softplus1(hs[128 + j]);
        float z = mu + sg * eps[(size_t)g*128 + j];
        out[o_mu + (size_t)g*128 + j] = mu;
        out[o_sg + (size_t)g*128 + j] = sg;
        if (j < 64) out[(size_t)g*64 + j] = z;
        else        out[o_zm + (size_t)g*64 + (j - 64)] = z;
    }
}

extern "C" void kernel_launch(void* const* d_in, const int* in_sizes, int n_in,
                              void* d_out, int out_size, void* d_ws, size_t ws_size,
                              hipStream_t stream) {
    const float* rgb  = (const float*)d_in[0];
    const float* pos  = (const float*)d_in[1];
    const float* W1l  = (const float*)d_in[3];
    const float* b1l  = (const float*)d_in[4];
    const float* W1g  = (const float*)d_in[5];
    const float* b1g  = (const float*)d_in[6];
    const float* W2l  = (const float*)d_in[7];
    const float* b2l  = (const float*)d_in[8];
    const float* W2g  = (const float*)d_in[9];
    const float* b2g  = (const float*)d_in[10];
    const float* W3l  = (const float*)d_in[11];
    const float* b3l  = (const float*)d_in[12];
    const float* W3g  = (const float*)d_in[13];
    const float* b3g  = (const float*)d_in[14];
    const float* Wlin = (const float*)d_in[15];
    const float* blin = (const float*)d_in[16];
    const float* eps  = (const float*)d_in[17];
    const int* cl1 = (const int*)d_in[19];
    const int* cl2 = (const int*)d_in[20];

    const int N  = in_sizes[19];
    const int G  = in_sizes[17] / 128;
    const int M1 = in_sizes[20];
    const int M2 = in_sizes[21];
    const int P  = N / G;

    char* ws = (char*)d_ws;
    auto al = [](size_t x){ return (x + 255) & ~(size_t)255; };
    size_t off = 0;
    float* ps1  = (float*)(ws + off); off = al(off + 12ull*M1);
    size_t uni  = ((size_t)64*M1 > (size_t)512*M2) ? (size_t)64*M1 : (size_t)512*M2;
    float* agg1 = (float*)(ws + off);      // agg1 [M1x16] ... later f2 [M2x128] (disjoint lifetimes)
    float* f2   = (float*)(ws + off);
    off = al(off + uni);
    float* cnt1 = (float*)(ws + off); off = al(off + 4ull*M1);
    float* ps2  = (float*)(ws + off); off = al(off + 12ull*M2);
    float* agg2 = (float*)(ws + off); off = al(off + 256ull*M2);
    float* cnt2 = (float*)(ws + off); off = al(off + 4ull*M2);
    float* agg3 = (float*)(ws + off); off = al(off + 512ull*G);
    int*   seg1 = (int*)  (ws + off); off = al(off + 8ull*G);
    int*   seg2 = (int*)  (ws + off); off = al(off + 8ull*G);
    if (off > ws_size) return;

    kA<<<G, 256, 0, stream>>>(rgb, pos, cl1, W1l, b1l, ps1, agg1, cnt1, seg1, P);
    kB<<<G, 256, 0, stream>>>(ps1, agg1, cl2, W1g, b1g, W2l, b2l, seg1, ps2, agg2, cnt2, seg2);
    int gx = (M2 + 127) / 128;
    k_f2f  <<<gx, 256, 0, stream>>>(agg2, W2g, b2g, f2, M2);
    dim3 g3((G + 1) / 2, 2);
    k_msg3g<<<g3, 256, 0, stream>>>(f2, ps2, seg2, W3l, b3l, agg3, G);
    k_head <<<G, 256, 0, stream>>>(agg3, W3g, b3g, Wlin, blin, eps, (float*)d_out, G);
}

// Round 6
// 397.540 us; speedup vs baseline: 8.8916x; 1.0665x over previous
//
#include <hip/hip_runtime.h>
#include <math.h>

#define N1CAP 736
#define N2CAP 192
#define S3 132   // padded row-stride for transposed x tiles

__device__ __forceinline__ float celu1(float x){ return x > 0.f ? x : (expf(x) - 1.f); }
__device__ __forceinline__ float softplus1(float x){ return fmaxf(x, 0.f) + log1pf(expf(-fabsf(x))); }
// valid only for v >= 0 with zero-initialized destination (works on LDS or global pointers)
__device__ __forceinline__ void atomicMaxNonneg(float* p, float v){
    atomicMax((int*)p, __float_as_int(v));
}

// ================= kernel A: per-glimpse stage 1, list-based (no compute atomics) =================
// Build per-voxel point lists in LDS (2 atomics/point), then one thread per voxel
// computes mean + 16 segmax channels entirely in registers. ~31 KB LDS -> 5 blocks/CU.
__global__ __launch_bounds__(256) void kA(const float* __restrict__ rgb,
                                          const float* __restrict__ pos,
                                          const int* __restrict__ cl1,
                                          const float* __restrict__ W1l,
                                          const float* __restrict__ b1l,
                                          float* __restrict__ ps1,
                                          float* __restrict__ agg1,
                                          float* __restrict__ cnt1,
                                          int* __restrict__ seg1, int P){
    __shared__ float sp[3*1024];        // 12 KB point positions
    __shared__ float srgb[1024];        // 4 KB
    __shared__ int   ci[1024];          // 4 KB raw cluster ids
    __shared__ int   cnt[N1CAP];
    __shared__ int   start[N1CAP+1];
    __shared__ int   cur[N1CAP];
    __shared__ unsigned short pidx[1024];
    __shared__ float wsh[64], bsh[16];
    __shared__ int   red[2];
    __shared__ int   wsum[4];
    const int g = blockIdx.x, tid = threadIdx.x;
    const int base = g * P;
    const bool pfit = (P <= 1024);

    if (tid == 0){ red[0] = 0x7fffffff; red[1] = -1; }
    if (tid < 64) wsh[tid] = W1l[tid];
    if (tid < 16) bsh[tid] = b1l[tid];
    __syncthreads();
    int mn = 0x7fffffff, mx = -1;
    for (int i = tid; i < P; i += 256){
        int c = cl1[base+i];
        if (pfit) ci[i] = c;
        mn = min(mn,c); mx = max(mx,c);
    }
    atomicMin(&red[0], mn); atomicMax(&red[1], mx);
    __syncthreads();
    const int s1 = red[0];
    const int n1 = red[1] - red[0] + 1;
    const bool fast = pfit && (n1 <= N1CAP);

    if (fast){
        // stage points + zero counts
        for (int t = tid; t < 3*P; t += 256) sp[t] = pos[(size_t)base*3 + t];
        for (int t = tid; t < P;   t += 256) srgb[t] = rgb[base + t];
        for (int l = tid; l < n1;  l += 256) cnt[l] = 0;
        __syncthreads();
        // count
        for (int i = tid; i < P; i += 256) atomicAdd(&cnt[ci[i] - s1], 1);
        __syncthreads();
        // block prefix scan (3 elems/thread, contiguous)
        {
            int b3 = tid*3;
            int a0 = (b3   < n1) ? cnt[b3]   : 0;
            int a1 = (b3+1 < n1) ? cnt[b3+1] : 0;
            int a2 = (b3+2 < n1) ? cnt[b3+2] : 0;
            int s = a0+a1+a2;
            int lane = tid & 63, wv = tid >> 6;
            int ps = s;
            #pragma unroll
            for (int d = 1; d < 64; d <<= 1){
                int t2 = __shfl_up(ps, d, 64);
                if (lane >= d) ps += t2;
            }
            if (lane == 63) wsum[wv] = ps;
            __syncthreads();
            int woff = 0;
            #pragma unroll
            for (int w = 0; w < 4; ++w) woff += (w < wv) ? wsum[w] : 0;
            int excl = woff + ps - s;
            if (b3   < n1){ start[b3]   = excl;       cur[b3]   = excl; }
            if (b3+1 < n1){ start[b3+1] = excl+a0;    cur[b3+1] = excl+a0; }
            if (b3+2 < n1){ start[b3+2] = excl+a0+a1; cur[b3+2] = excl+a0+a1; }
            if (tid == 0) start[n1] = P;
        }
        __syncthreads();
        // scatter point indices
        for (int i = tid; i < P; i += 256){
            int slot = atomicAdd(&cur[ci[i] - s1], 1);
            pidx[slot] = (unsigned short)i;
        }
        __syncthreads();
        // one thread per voxel: mean + 16-channel segmax, zero atomics
        for (int l = tid; l < n1; l += 256){
            int s0 = start[l], e0 = start[l+1];
            float sxv=0.f, syv=0.f, szv=0.f;
            for (int k = s0; k < e0; ++k){
                int i = pidx[k];
                sxv += sp[3*i+0]; syv += sp[3*i+1]; szv += sp[3*i+2];
            }
            float ic = 1.0f / (float)max(e0 - s0, 1);
            float mxp = sxv*ic, myp = syv*ic, mzp = szv*ic;
            ps1[(size_t)(s1+l)*3+0] = mxp;
            ps1[(size_t)(s1+l)*3+1] = myp;
            ps1[(size_t)(s1+l)*3+2] = mzp;
            float acc[16];
            #pragma unroll
            for (int j = 0; j < 16; ++j) acc[j] = 0.f;
            for (int k = s0; k < e0; ++k){
                int i = pidx[k];
                float in0 = srgb[i];
                float r0 = sp[3*i+0] - mxp;
                float r1 = sp[3*i+1] - myp;
                float r2 = sp[3*i+2] - mzp;
                #pragma unroll
                for (int j = 0; j < 16; ++j){
                    float v = bsh[j] + in0*wsh[j] + r0*wsh[16+j] + r1*wsh[32+j] + r2*wsh[48+j];
                    acc[j] = fmaxf(acc[j], fmaxf(v, 0.f));
                }
            }
            float4* dst = (float4*)&agg1[(size_t)(s1+l)*16];
            dst[0] = make_float4(acc[0], acc[1], acc[2], acc[3]);
            dst[1] = make_float4(acc[4], acc[5], acc[6], acc[7]);
            dst[2] = make_float4(acc[8], acc[9], acc[10], acc[11]);
            dst[3] = make_float4(acc[12], acc[13], acc[14], acc[15]);
        }
    } else {
        // rare fallback: global atomics into this block's exclusive rows
        for (int t = tid; t < n1;    t += 256) cnt1[s1+t] = 0.f;
        for (int t = tid; t < n1*3;  t += 256) ps1[(size_t)s1*3+t] = 0.f;
        for (int t = tid; t < n1*16; t += 256) agg1[(size_t)s1*16+t] = 0.f;
        __syncthreads();
        for (int i = tid; i < P; i += 256){
            int idx = base + i; int c = cl1[idx];
            atomicAdd(&ps1[3*c+0], pos[3*idx+0]);
            atomicAdd(&ps1[3*c+1], pos[3*idx+1]);
            atomicAdd(&ps1[3*c+2], pos[3*idx+2]);
            atomicAdd(&cnt1[c], 1.0f);
        }
        __syncthreads();
        for (int l = tid; l < n1; l += 256){
            float ic = 1.0f / fmaxf(cnt1[s1+l], 1.0f);
            ps1[(size_t)(s1+l)*3+0] *= ic; ps1[(size_t)(s1+l)*3+1] *= ic; ps1[(size_t)(s1+l)*3+2] *= ic;
        }
        __syncthreads();
        for (int i = tid; i < P; i += 256){
            int idx = base + i; int c = cl1[idx];
            float in0 = rgb[idx];
            float r0 = pos[3*idx+0] - ps1[3*c+0];
            float r1 = pos[3*idx+1] - ps1[3*c+1];
            float r2 = pos[3*idx+2] - ps1[3*c+2];
            #pragma unroll
            for (int j = 0; j < 16; ++j){
                float v = b1l[j] + in0*W1l[j] + r0*W1l[16+j] + r1*W1l[32+j] + r2*W1l[48+j];
                atomicMaxNonneg(&agg1[(size_t)c*16+j], fmaxf(v, 0.0f));
            }
        }
    }
    if (tid == 0){ seg1[2*g] = s1; seg1[2*g+1] = n1; }
}

// ================= kernel B: per-glimpse stage 2, 4-way ILP =================
__global__ __launch_bounds__(256) void kB(const float* __restrict__ ps1,
                                          const float* __restrict__ agg1,
                                          const int* __restrict__ cl2,
                                          const float* __restrict__ W1g,
                                          const float* __restrict__ b1g,
                                          const float* __restrict__ W2l,
                                          const float* __restrict__ b2l,
                                          const int* __restrict__ seg1,
                                          float* __restrict__ ps2,
                                          float* __restrict__ agg2,
                                          float* __restrict__ cnt2,
                                          int* __restrict__ seg2){
    __shared__ float sx[N2CAP], sy[N2CAP], sz[N2CAP], sc[N2CAP];
    __shared__ float sagg[N2CAP*64];
    __shared__ int red[2];
    const int g = blockIdx.x, tid = threadIdx.x;
    const int s1 = seg1[2*g], n1 = seg1[2*g+1], e1 = s1 + n1;

    if (tid == 0){ red[0] = 0x7fffffff; red[1] = -1; }
    __syncthreads();
    int mn = 0x7fffffff, mx = -1;
    for (int m = s1 + tid; m < e1; m += 256){ int c = cl2[m]; mn = min(mn,c); mx = max(mx,c); }
    atomicMin(&red[0], mn); atomicMax(&red[1], mx);
    __syncthreads();
    const int s2 = red[0];
    const int n2 = red[1] - red[0] + 1;
    const bool fast = (n2 <= N2CAP);

    if (fast){
        for (int l = tid; l < n2; l += 256){ sx[l]=0.f; sy[l]=0.f; sz[l]=0.f; sc[l]=0.f; }
        for (int t = tid; t < n2*64; t += 256) sagg[t] = 0.f;
        __syncthreads();
        for (int m = s1 + tid; m < e1; m += 256){
            int c = cl2[m] - s2;
            atomicAdd(&sx[c], ps1[3*m+0]);
            atomicAdd(&sy[c], ps1[3*m+1]);
            atomicAdd(&sz[c], ps1[3*m+2]);
            atomicAdd(&sc[c], 1.0f);
        }
        __syncthreads();
        for (int l = tid; l < n2; l += 256){
            float ic = 1.0f / sc[l];
            sx[l] *= ic; sy[l] *= ic; sz[l] *= ic;
        }
        __syncthreads();
        for (int t = tid; t < n2*3; t += 256){
            int l = t/3, d = t - 3*l;
            ps2[(size_t)s2*3 + t] = (d==0) ? sx[l] : ((d==1) ? sy[l] : sz[l]);
        }
        for (int m = s1 + tid; m < e1; m += 256){
            float a[16];
            const float* ar = agg1 + (size_t)m*16;
            #pragma unroll
            for (int k = 0; k < 16; ++k) a[k] = ar[k];
            float in[35];
            // f1 = celu(a @ W1g + b1g): 4 independent accumulator chains
            for (int j = 0; j < 32; j += 4){
                float v0=b1g[j+0], v1=b1g[j+1], v2=b1g[j+2], v3=b1g[j+3];
                #pragma unroll
                for (int k = 0; k < 16; ++k){
                    float x = a[k];
                    const float* w = &W1g[k*32 + j];
                    v0 += x*w[0]; v1 += x*w[1]; v2 += x*w[2]; v3 += x*w[3];
                }
                in[j+0]=celu1(v0); in[j+1]=celu1(v1); in[j+2]=celu1(v2); in[j+3]=celu1(v3);
            }
            int c = cl2[m] - s2;
            in[32] = ps1[3*m+0] - sx[c];
            in[33] = ps1[3*m+1] - sy[c];
            in[34] = ps1[3*m+2] - sz[c];
            float* dst = &sagg[c*64];
            for (int j = 0; j < 64; j += 4){
                float v0=b2l[j+0], v1=b2l[j+1], v2=b2l[j+2], v3=b2l[j+3];
                #pragma unroll
                for (int k = 0; k < 35; ++k){
                    float x = in[k];
                    const float* w = &W2l[k*64 + j];
                    v0 += x*w[0]; v1 += x*w[1]; v2 += x*w[2]; v3 += x*w[3];
                }
                atomicMaxNonneg(&dst[(j+0 + c) & 63], fmaxf(v0, 0.0f));
                atomicMaxNonneg(&dst[(j+1 + c) & 63], fmaxf(v1, 0.0f));
                atomicMaxNonneg(&dst[(j+2 + c) & 63], fmaxf(v2, 0.0f));
                atomicMaxNonneg(&dst[(j+3 + c) & 63], fmaxf(v3, 0.0f));
            }
        }
        __syncthreads();
        for (int t = tid; t < n2*64; t += 256){
            int l = t >> 6, j = t & 63;
            agg2[(size_t)s2*64 + t] = sagg[l*64 + ((j + l) & 63)];
        }
    } else {
        for (int t = tid; t < n2;    t += 256) cnt2[s2+t] = 0.f;
        for (int t = tid; t < n2*3;  t += 256) ps2[(size_t)s2*3+t] = 0.f;
        for (int t = tid; t < n2*64; t += 256) agg2[(size_t)s2*64+t] = 0.f;
        __syncthreads();
        for (int m = s1 + tid; m < e1; m += 256){
            int c = cl2[m];
            atomicAdd(&ps2[3*c+0], ps1[3*m+0]);
            atomicAdd(&ps2[3*c+1], ps1[3*m+1]);
            atomicAdd(&ps2[3*c+2], ps1[3*m+2]);
            atomicAdd(&cnt2[c], 1.0f);
        }
        __syncthreads();
        for (int l = tid; l < n2; l += 256){
            float ic = 1.0f / fmaxf(cnt2[s2+l], 1.0f);
            ps2[(size_t)(s2+l)*3+0] *= ic; ps2[(size_t)(s2+l)*3+1] *= ic; ps2[(size_t)(s2+l)*3+2] *= ic;
        }
        __syncthreads();
        for (int m = s1 + tid; m < e1; m += 256){
            float a[16];
            const float* ar = agg1 + (size_t)m*16;
            #pragma unroll
            for (int k = 0; k < 16; ++k) a[k] = ar[k];
            float in[35];
            #pragma unroll
            for (int j = 0; j < 32; ++j){
                float v = b1g[j];
                #pragma unroll
                for (int k = 0; k < 16; ++k) v += a[k] * W1g[k*32+j];
                in[j] = celu1(v);
            }
            int c = cl2[m];
            in[32] = ps1[3*m+0] - ps2[3*c+0];
            in[33] = ps1[3*m+1] - ps2[3*c+1];
            in[34] = ps1[3*m+2] - ps2[3*c+2];
            for (int j = 0; j < 64; ++j){
                float v = b2l[j];
                #pragma unroll
                for (int k = 0; k < 35; ++k) v += in[k] * W2l[k*64+j];
                atomicMaxNonneg(&agg2[(size_t)c*64+j], fmaxf(v, 0.0f));
            }
        }
    }
    if (tid == 0){ seg2[2*g] = s2; seg2[2*g+1] = n2; }
}

// ================= flat GEMM: f2 = celu(agg2[M2x64] @ W2g + b2g) =================
__global__ __launch_bounds__(256) void k_f2f(const float* __restrict__ agg2,
                                             const float* __restrict__ W2g,
                                             const float* __restrict__ b2g,
                                             float* __restrict__ f2, int M2){
    __shared__ float Ws[64*128];   // 32 KB, [k][128]
    __shared__ float xt[32*S3];    // 16.9 KB
    const int tid = threadIdx.x;
    const int m0 = blockIdx.x * 128;
    for (int t = tid; t < 64*128; t += 256) Ws[t] = W2g[t];
    const int tr = tid & 31, tc = tid >> 5;
    float acc[4][16];
    #pragma unroll
    for (int c = 0; c < 16; ++c){
        float b = b2g[tc*16 + c];
        #pragma unroll
        for (int r = 0; r < 4; ++r) acc[r][c] = b;
    }
    for (int c0 = 0; c0 < 64; c0 += 32){
        __syncthreads();
        for (int t = tid; t < 128*8; t += 256){
            int row = t >> 3, kq = t & 7;
            int m = m0 + row;
            float4 v = (m < M2) ? *(const float4*)&agg2[(size_t)m*64 + c0 + kq*4]
                                : make_float4(0.f,0.f,0.f,0.f);
            xt[(kq*4+0)*S3 + row] = v.x;
            xt[(kq*4+1)*S3 + row] = v.y;
            xt[(kq*4+2)*S3 + row] = v.z;
            xt[(kq*4+3)*S3 + row] = v.w;
        }
        __syncthreads();
        #pragma unroll 4
        for (int kk = 0; kk < 32; ++kk){
            int k = c0 + kk;
            float4 xr = *(const float4*)&xt[kk*S3 + tr*4];
            float xv[4] = {xr.x, xr.y, xr.z, xr.w};
            float wv[16];
            #pragma unroll
            for (int q = 0; q < 4; ++q){
                float4 w = *(const float4*)&Ws[k*128 + tc*16 + q*4];
                wv[q*4+0]=w.x; wv[q*4+1]=w.y; wv[q*4+2]=w.z; wv[q*4+3]=w.w;
            }
            #pragma unroll
            for (int r = 0; r < 4; ++r)
                #pragma unroll
                for (int c = 0; c < 16; ++c) acc[r][c] += xv[r]*wv[c];
        }
    }
    #pragma unroll
    for (int r = 0; r < 4; ++r){
        int m = m0 + tr*4 + r;
        if (m < M2){
            #pragma unroll
            for (int q = 0; q < 4; ++q){
                float4 o;
                o.x = celu1(acc[r][q*4+0]); o.y = celu1(acc[r][q*4+1]);
                o.z = celu1(acc[r][q*4+2]); o.w = celu1(acc[r][q*4+3]);
                *(float4*)&f2[(size_t)m*128 + tc*16 + q*4] = o;
            }
        }
    }
}

// ================= stage-3 GEMM + block-local segmax, zero global atomics =================
__global__ __launch_bounds__(256) void k_msg3g(const float* __restrict__ f2,
                                               const float* __restrict__ ps2,
                                               const int* __restrict__ seg2,
                                               const float* __restrict__ W3l,
                                               const float* __restrict__ b3l,
                                               float* __restrict__ agg3, int G){
    __shared__ float Wh[131*64];   // 33.5 KB column half
    __shared__ float xt[32*S3];    // 16.9 KB
    __shared__ float shAgg[128];   // [2 glimpses][64 ch]
    const int tid = threadIdx.x;
    const int cb = blockIdx.y * 64;
    const int g0 = blockIdx.x * 2;
    const int S  = seg2[2*g0];
    const int B  = seg2[2*g0+1];
    const int n2b = (g0 + 1 < G) ? seg2[2*g0+3] : 0;
    const int T  = B + n2b;
    for (int t = tid; t < 131*64; t += 256){
        int k = t >> 6, c = t & 63;
        Wh[t] = W3l[k*128 + cb + c];
    }
    if (tid < 128) shAgg[tid] = 0.f;
    const int tr = tid & 31, tc = tid >> 5;
    float bias[8];
    #pragma unroll
    for (int c = 0; c < 8; ++c) bias[c] = b3l[cb + tc*8 + c];

    for (int w0 = 0; w0 < T; w0 += 128){
        float acc[4][8];
        #pragma unroll
        for (int r = 0; r < 4; ++r)
            #pragma unroll
            for (int c = 0; c < 8; ++c) acc[r][c] = bias[c];
        for (int c0 = 0; c0 < 128; c0 += 32){
            __syncthreads();
            for (int t = tid; t < 128*8; t += 256){
                int row = t >> 3, kq = t & 7;
                int ridx = w0 + row;
                float4 v = (ridx < T) ? *(const float4*)&f2[(size_t)(S+ridx)*128 + c0 + kq*4]
                                      : make_float4(0.f,0.f,0.f,0.f);
                xt[(kq*4+0)*S3 + row] = v.x;
                xt[(kq*4+1)*S3 + row] = v.y;
                xt[(kq*4+2)*S3 + row] = v.z;
                xt[(kq*4+3)*S3 + row] = v.w;
            }
            __syncthreads();
            #pragma unroll 8
            for (int kk = 0; kk < 32; ++kk){
                int k = c0 + kk;
                float4 xr = *(const float4*)&xt[kk*S3 + tr*4];
                float xv[4] = {xr.x, xr.y, xr.z, xr.w};
                float4 wa = *(const float4*)&Wh[k*64 + tc*8];
                float4 wb = *(const float4*)&Wh[k*64 + tc*8 + 4];
                float wv[8] = {wa.x,wa.y,wa.z,wa.w, wb.x,wb.y,wb.z,wb.w};
                #pragma unroll
                for (int r = 0; r < 4; ++r)
                    #pragma unroll
                    for (int c = 0; c < 8; ++c) acc[r][c] += xv[r]*wv[c];
            }
        }
        #pragma unroll
        for (int kk = 0; kk < 3; ++kk){
            const float* w = &Wh[(128+kk)*64 + tc*8];
            float wv[8];
            #pragma unroll
            for (int c = 0; c < 8; ++c) wv[c] = w[c];
            #pragma unroll
            for (int r = 0; r < 4; ++r){
                int ridx = w0 + tr*4 + r;
                float x = (ridx < T) ? ps2[(size_t)(S+ridx)*3 + kk] : 0.f;
                #pragma unroll
                for (int c = 0; c < 8; ++c) acc[r][c] += x*wv[c];
            }
        }
        float mx0[8], mx1[8];
        #pragma unroll
        for (int c = 0; c < 8; ++c){ mx0[c] = 0.f; mx1[c] = 0.f; }
        bool h0 = false, h1 = false;
        #pragma unroll
        for (int r = 0; r < 4; ++r){
            int ridx = w0 + tr*4 + r;
            if (ridx < T){
                bool second = (ridx >= B);
                h0 |= !second; h1 |= second;
                #pragma unroll
                for (int c = 0; c < 8; ++c){
                    float v = fmaxf(acc[r][c], 0.f);
                    mx0[c] = fmaxf(mx0[c], second ? 0.f : v);
                    mx1[c] = fmaxf(mx1[c], second ? v : 0.f);
                }
            }
        }
        if (h0){
            #pragma unroll
            for (int c = 0; c < 8; ++c) atomicMaxNonneg(&shAgg[tc*8 + c], mx0[c]);
        }
        if (h1){
            #pragma unroll
            for (int c = 0; c < 8; ++c) atomicMaxNonneg(&shAgg[64 + tc*8 + c], mx1[c]);
        }
    }
    __syncthreads();
    if (tid < 128){
        int loc = tid >> 6, c = tid & 63;
        int g = g0 + loc;
        if (loc == 0 || n2b > 0)
            agg3[(size_t)g*128 + cb + c] = shAgg[loc*64 + c];
    }
}

// ================= head =================
__global__ __launch_bounds__(256) void k_head(const float* __restrict__ agg3,
                                              const float* __restrict__ W3g,
                                              const float* __restrict__ b3g,
                                              const float* __restrict__ Wlin,
                                              const float* __restrict__ blin,
                                              const float* __restrict__ eps,
                                              float* __restrict__ out, int G){
    __shared__ float a3[128];
    __shared__ float f3s[256];
    __shared__ float hs[256];
    int g = blockIdx.x;
    int j = threadIdx.x;
    if (j < 128) a3[j] = agg3[(size_t)g*128 + j];
    __syncthreads();

    float v = b3g[j];
    for (int k = 0; k < 128; ++k) v += a3[k] * W3g[k*256 + j];
    v = celu1(v);
    f3s[j] = v;
    const size_t o_zm = (size_t)64*G, o_mu = (size_t)128*G, o_sg = (size_t)256*G, o_f3 = (size_t)384*G;
    out[o_f3 + (size_t)g*256 + j] = v;
    __syncthreads();

    float h = blin[j];
    for (int k = 0; k < 256; ++k) h += f3s[k] * Wlin[k*256 + j];
    hs[j] = h;
    __syncthreads();

    if (j < 128){
        float mu = hs[j];
        float sg = softplus1(hs[128 + j]);
        float z = mu + sg * eps[(size_t)g*128 + j];
        out[o_mu + (size_t)g*128 + j] = mu;
        out[o_sg + (size_t)g*128 + j] = sg;
        if (j < 64) out[(size_t)g*64 + j] = z;
        else        out[o_zm + (size_t)g*64 + (j - 64)] = z;
    }
}

extern "C" void kernel_launch(void* const* d_in, const int* in_sizes, int n_in,
                              void* d_out, int out_size, void* d_ws, size_t ws_size,
                              hipStream_t stream) {
    const float* rgb  = (const float*)d_in[0];
    const float* pos  = (const float*)d_in[1];
    const float* W1l  = (const float*)d_in[3];
    const float* b1l  = (const float*)d_in[4];
    const float* W1g  = (const float*)d_in[5];
    const float* b1g  = (const float*)d_in[6];
    const float* W2l  = (const float*)d_in[7];
    const float* b2l  = (const float*)d_in[8];
    const float* W2g  = (const float*)d_in[9];
    const float* b2g  = (const float*)d_in[10];
    const float* W3l  = (const float*)d_in[11];
    const float* b3l  = (const float*)d_in[12];
    const float* W3g  = (const float*)d_in[13];
    const float* b3g  = (const float*)d_in[14];
    const float* Wlin = (const float*)d_in[15];
    const float* blin = (const float*)d_in[16];
    const float* eps  = (const float*)d_in[17];
    const int* cl1 = (const int*)d_in[19];
    const int* cl2 = (const int*)d_in[20];

    const int N  = in_sizes[19];
    const int G  = in_sizes[17] / 128;
    const int M1 = in_sizes[20];
    const int M2 = in_sizes[21];
    const int P  = N / G;

    char* ws = (char*)d_ws;
    auto al = [](size_t x){ return (x + 255) & ~(size_t)255; };
    size_t off = 0;
    float* ps1  = (float*)(ws + off); off = al(off + 12ull*M1);
    size_t uni  = ((size_t)64*M1 > (size_t)512*M2) ? (size_t)64*M1 : (size_t)512*M2;
    float* agg1 = (float*)(ws + off);      // agg1 [M1x16] ... later f2 [M2x128] (disjoint lifetimes)
    float* f2   = (float*)(ws + off);
    off = al(off + uni);
    float* cnt1 = (float*)(ws + off); off = al(off + 4ull*M1);
    float* ps2  = (float*)(ws + off); off = al(off + 12ull*M2);
    float* agg2 = (float*)(ws + off); off = al(off + 256ull*M2);
    float* cnt2 = (float*)(ws + off); off = al(off + 4ull*M2);
    float* agg3 = (float*)(ws + off); off = al(off + 512ull*G);
    int*   seg1 = (int*)  (ws + off); off = al(off + 8ull*G);
    int*   seg2 = (int*)  (ws + off); off = al(off + 8ull*G);
    if (off > ws_size) return;

    kA<<<G, 256, 0, stream>>>(rgb, pos, cl1, W1l, b1l, ps1, agg1, cnt1, seg1, P);
    kB<<<G, 256, 0, stream>>>(ps1, agg1, cl2, W1g, b1g, W2l, b2l, seg1, ps2, agg2, cnt2, seg2);
    int gx = (M2 + 127) / 128;
    k_f2f  <<<gx, 256, 0, stream>>>(agg2, W2g, b2g, f2, M2);
    dim3 g3((G + 1) / 2, 2);
    k_msg3g<<<g3, 256, 0, stream>>>(f2, ps2, seg2, W3l, b3l, agg3, G);
    k_head <<<G, 256, 0, stream>>>(agg3, W3g, b3g, Wlin, blin, eps, (float*)d_out, G);
}